// Round 12
// baseline (389.301 us; speedup 1.0000x reference)
//
#include <hip/hip_runtime.h>
#include <math.h>

#define GH 128
#define GW 128
#define HWC 16384
#define NMODE 1152
#define PI_F 3.14159265358979323846f

typedef _Float16 f16;
typedef __attribute__((ext_vector_type(8))) _Float16 f16x8;
typedef __attribute__((ext_vector_type(4))) float f32x4;

__device__ __forceinline__ float gelu_f(float x) {
  return 0.5f * x * (1.0f + erff(x * 0.70710678118654752f));
}

// ---------------- prep: twiddle tables + f16-transposed p1 ----------------
__global__ __launch_bounds__(256) void k_twiddle(f16* __restrict__ Fw, f16* __restrict__ Fh,
                                                 f16* __restrict__ Bh, f16* __restrict__ Bw,
                                                 const float* __restrict__ p1w, f16* __restrict__ p1t)
{
  int idx = blockIdx.x * 256 + threadIdx.x;
  if (idx < 6144) {
    int n = idx >> 7, w = idx & 127;
    int ky = n >> 1;
    int ang = (ky * w) & 127;
    float s, c; sincosf((float)ang * (PI_F / 64.f), &s, &c);
    Fw[idx] = (f16)((n & 1) ? -s : c);
  } else if (idx < 18432) {
    int t = idx - 6144;
    int n = t >> 7, h = t & 127;
    int kx = n < 48 ? n : n - 48;
    int f = kx < 24 ? kx : kx + 80;
    int ang = (f * h) & 127;
    float s, c; sincosf((float)ang * (PI_F / 64.f), &s, &c);
    float v = (n < 48) ? c : s;
    Fh[t] = (f16)v;
    Bh[h * 96 + n] = (f16)v;
  } else if (idx < 26624) {
    int t = idx - 18432;
    int w = t >> 6, k = t & 63;
    float v = 0.f;
    if (k < 48 && k != 1) {
      int ky = k >> 1;
      float g = (ky == 0) ? 1.f : 2.f;
      int ang = (ky * w) & 127;
      float s, c; sincosf((float)ang * (PI_F / 64.f), &s, &c);
      v = (k & 1) ? -g * s : g * c;
    }
    Bw[t] = (f16)v;
  } else if (idx < 34816) {
    int t = idx - 26624;          // t = j*64 + i
    int j = t >> 6, i = t & 63;
    p1t[t] = (f16)p1w[i * 128 + j];
  }
}

// ---------------- points: deform MLP (f32) + rank atomic + bilinear data ----------------
__global__ __launch_bounds__(256) void k_points(
    const float* __restrict__ coords,
    const float* __restrict__ dw0, const float* __restrict__ db0,
    const float* __restrict__ dw1, const float* __restrict__ db1,
    const float* __restrict__ dw2, const float* __restrict__ db2,
    int* __restrict__ cnt_i,
    int* __restrict__ ptrank, int* __restrict__ pd_cell,
    int* __restrict__ pd_idx, float* __restrict__ pd_th, float* __restrict__ pd_tw)
{
  int pid = blockIdx.x * 256 + threadIdx.x;
  float2 c = ((const float2*)coords)[pid];

  float h1[32];
#pragma unroll
  for (int j = 0; j < 32; ++j)
    h1[j] = gelu_f(fmaf(c.x, dw0[j], fmaf(c.y, dw0[32 + j], db0[j])));

  float a[32];
#pragma unroll
  for (int j = 0; j < 32; ++j) a[j] = db1[j];
#pragma unroll 4
  for (int k = 0; k < 32; ++k) {
    float hk = h1[k];
    const float* wr = dw1 + k * 32;
#pragma unroll
    for (int j = 0; j < 32; ++j) a[j] = fmaf(hk, wr[j], a[j]);
  }

  float d0 = db2[0], d1 = db2[1];
#pragma unroll 4
  for (int k = 0; k < 32; ++k) {
    float hk = gelu_f(a[k]);
    d0 = fmaf(hk, dw2[2 * k], d0);
    d1 = fmaf(hk, dw2[2 * k + 1], d1);
  }

  float l0 = fminf(fmaxf(c.x + d0, -1.f), 1.f);
  float l1 = fminf(fmaxf(c.y + d1, -1.f), 1.f);
  float ph = (l0 + 1.f) * 0.5f * 127.f;
  float pw = (l1 + 1.f) * 0.5f * 127.f;
  int ih = min(max((int)rintf(ph), 0), 127);
  int iw = min(max((int)rintf(pw), 0), 127);
  int b = pid >> 14;
  int cell = b * HWC + ih * GW + iw;

  int r = atomicAdd(&cnt_i[cell], 1);
  ptrank[pid] = r;
  pd_cell[pid] = cell;

  float fh = floorf(ph), fw = floorf(pw);
  int h0i = min(max((int)fh, 0), 127), w0i = min(max((int)fw, 0), 127);
  pd_idx[pid] = h0i | (w0i << 8);
  pd_th[pid] = ph - fh;
  pd_tw[pid] = pw - fw;
}

// ---------------- scans ----------------
__global__ __launch_bounds__(256) void k_scanA(const int* __restrict__ cnt,
                                               int* __restrict__ starts, int* __restrict__ btot)
{
  __shared__ int sh[256];
  int blk = blockIdx.x, t = threadIdx.x;
  int base = blk * 512;
  int v0 = cnt[base + 2 * t], v1 = cnt[base + 2 * t + 1];
  int pair = v0 + v1;
  sh[t] = pair; __syncthreads();
  int acc = pair;
  for (int off = 1; off < 256; off <<= 1) {
    int add = (t >= off) ? sh[t - off] : 0;
    __syncthreads();
    acc += add; sh[t] = acc;
    __syncthreads();
  }
  int excl = acc - pair;
  starts[base + 2 * t] = excl;
  starts[base + 2 * t + 1] = excl + v0;
  if (t == 255) btot[blk] = acc;
}

__global__ __launch_bounds__(256) void k_scanB(const int* __restrict__ btot, int* __restrict__ boff)
{
  __shared__ int sh[256];
  int t = threadIdx.x;
  int v = btot[t];
  sh[t] = v; __syncthreads();
  int acc = v;
  for (int off = 1; off < 256; off <<= 1) {
    int add = (t >= off) ? sh[t - off] : 0;
    __syncthreads();
    acc += add; sh[t] = acc;
    __syncthreads();
  }
  boff[t] = acc - v;
}

// ---------------- permute ----------------
__global__ __launch_bounds__(256) void k_perm(const int* __restrict__ pd_cell, const int* __restrict__ ptrank,
                                              const int* __restrict__ starts, const int* __restrict__ boff,
                                              const int* __restrict__ pd_idx, const float* __restrict__ pd_th,
                                              const float* __restrict__ pd_tw,
                                              const float* __restrict__ coords, const float* __restrict__ feats,
                                              int4* __restrict__ pds,
                                              float4* __restrict__ scA, float* __restrict__ scB)
{
  int pid = blockIdx.x * 256 + threadIdx.x;
  int cell = pd_cell[pid];
  int dst = starts[cell] + boff[cell >> 9] + ptrank[pid];
  int4 rec;
  rec.x = pid;
  rec.y = pd_idx[pid];
  rec.z = __float_as_int(pd_th[pid]);
  rec.w = __float_as_int(pd_tw[pid]);
  pds[dst] = rec;
  float2 c = ((const float2*)coords)[pid];
  scA[dst] = make_float4(feats[pid * 3], feats[pid * 3 + 1], feats[pid * 3 + 2], c.x);
  scB[dst] = c.y;
}

// ---------------- segmented cell-sum + lift -> Gh (f16) ----------------
__global__ __launch_bounds__(256) void k_gridlift(const float4* __restrict__ scA, const float* __restrict__ scB,
                                                  const int* __restrict__ starts, const int* __restrict__ boff,
                                                  const int* __restrict__ cnt_i,
                                                  const float* __restrict__ lw,
                                                  const float* __restrict__ lb,
                                                  f16* __restrict__ Gh)
{
  __shared__ float sp[2][128][5];
  __shared__ float s_lw[5][64];
  __shared__ float s_lb[64];
  __shared__ float s_cnt[128];
  int b = blockIdx.y, cbase = blockIdx.x * 128, tid = threadIdx.x;
  int cl = tid & 127, par = tid >> 7;
  int gcell = b * HWC + cbase + cl;
  int start = starts[gcell] + boff[gcell >> 9];
  int cnt = cnt_i[gcell];
  float a0 = 0.f, a1 = 0.f, a2 = 0.f, a3 = 0.f, a4 = 0.f;
  for (int p = start + par; p < start + cnt; p += 2) {
    float4 A = scA[p];
    a0 += A.x; a1 += A.y; a2 += A.z; a3 += A.w; a4 += scB[p];
  }
  sp[par][cl][0] = a0; sp[par][cl][1] = a1; sp[par][cl][2] = a2;
  sp[par][cl][3] = a3; sp[par][cl][4] = a4;
  if (par == 0) s_cnt[cl] = (float)cnt;
  for (int l = tid; l < 320; l += 256) ((float*)s_lw)[l] = lw[l];
  if (tid < 64) s_lb[tid] = lb[tid];
  __syncthreads();
  float v0 = sp[0][cl][0] + sp[1][cl][0];
  float v1 = sp[0][cl][1] + sp[1][cl][1];
  float v2 = sp[0][cl][2] + sp[1][cl][2];
  float v3 = sp[0][cl][3] + sp[1][cl][3];
  float v4 = sp[0][cl][4] + sp[1][cl][4];
  float cntf = s_cnt[cl];
  float inv = 1.f / fmaxf(cntf, 1.f);
  int oh = tid >> 7;
#pragma unroll
  for (int j = 0; j < 32; ++j) {
    int o = oh * 32 + j;
    float val = cntf * s_lb[o];
    val = fmaf(v0, s_lw[0][o], val);
    val = fmaf(v1, s_lw[1][o], val);
    val = fmaf(v2, s_lw[2][o], val);
    val = fmaf(v3, s_lw[3][o], val);
    val = fmaf(v4, s_lw[4][o], val);
    Gh[(size_t)(b * 64 + o) * HWC + cbase + cl] = (f16)(val * inv);
  }
}

// ---------------- fused forward DFT (blocks 0..511) + pointwise conv (blocks 512..1023) ----------------
__global__ __launch_bounds__(256) void k_fwdpw(const f16* __restrict__ Gh,
                                               const f16* __restrict__ Fw_t, const f16* __restrict__ Fh_t,
                                               float2* __restrict__ Xf2,
                                               const float* __restrict__ pww, const float* __restrict__ pwb,
                                               f16* __restrict__ yh)
{
  __shared__ char smem[52224];
  int tid = threadIdx.x;
  int wave = tid >> 6, lane = tid & 63, lr = lane & 15, lg = lane >> 4;

  if (blockIdx.x < 512) {
    // ---- forward DFT ----
    f16 (*s_fw)[136]  = (f16(*)[136])smem;
    f16 (*s_img)[136] = (f16(*)[136])(smem + 13056);
    f16 (*s_xw)[136]  = (f16(*)[136])(smem + 13056);
    f16 (*s_fh)[136]  = (f16(*)[136])(smem + 13056 + 48 * 136 * 2);
    int bc = blockIdx.x;
    for (int l = tid; l < 2048; l += 256) {
      int r = l >> 4, c = l & 15;
      *(f16x8*)&s_img[r][c * 8] = *(const f16x8*)(Gh + (size_t)bc * HWC + r * 128 + c * 8);
    }
    for (int l = tid; l < 768; l += 256) {
      int r = l >> 4, c = l & 15;
      *(f16x8*)&s_fw[r][c * 8] = *(const f16x8*)(Fw_t + r * 128 + c * 8);
    }
    __syncthreads();

    f32x4 acc1[2][3] = {};
#pragma unroll
    for (int ks = 0; ks < 4; ++ks) {
      f16x8 a[2], b[3];
#pragma unroll
      for (int mm = 0; mm < 2; ++mm) a[mm] = *(const f16x8*)&s_img[(wave * 2 + mm) * 16 + lr][ks * 32 + lg * 8];
#pragma unroll
      for (int nt = 0; nt < 3; ++nt) b[nt] = *(const f16x8*)&s_fw[nt * 16 + lr][ks * 32 + lg * 8];
#pragma unroll
      for (int mm = 0; mm < 2; ++mm)
#pragma unroll
        for (int nt = 0; nt < 3; ++nt)
          acc1[mm][nt] = __builtin_amdgcn_mfma_f32_16x16x32_f16(a[mm], b[nt], acc1[mm][nt], 0, 0, 0);
    }
    __syncthreads();
#pragma unroll
    for (int mm = 0; mm < 2; ++mm)
#pragma unroll
      for (int nt = 0; nt < 3; ++nt) {
        int n = nt * 16 + lr;
        int h0 = (wave * 2 + mm) * 16 + lg * 4;
#pragma unroll
        for (int r = 0; r < 4; ++r) s_xw[n][h0 + r] = (f16)acc1[mm][nt][r];
      }
    for (int l = tid; l < 1536; l += 256) {
      int r = l >> 4, c = l & 15;
      *(f16x8*)&s_fh[r][c * 8] = *(const f16x8*)(Fh_t + r * 128 + c * 8);
    }
    __syncthreads();

    for (int u = wave; u < 9; u += 4) {
      int mt = u / 3, ntC = u - mt * 3;
      f32x4 accC = {}, accS = {};
#pragma unroll
      for (int ks = 0; ks < 4; ++ks) {
        f16x8 a  = *(const f16x8*)&s_xw[mt * 16 + lr][ks * 32 + lg * 8];
        f16x8 bC = *(const f16x8*)&s_fh[ntC * 16 + lr][ks * 32 + lg * 8];
        f16x8 bS = *(const f16x8*)&s_fh[(ntC + 3) * 16 + lr][ks * 32 + lg * 8];
        accC = __builtin_amdgcn_mfma_f32_16x16x32_f16(a, bC, accC, 0, 0, 0);
        accS = __builtin_amdgcn_mfma_f32_16x16x32_f16(a, bS, accS, 0, 0, 0);
      }
      int kx = ntC * 16 + lr;
      int ky0 = (mt * 16 + lg * 4) >> 1;
      Xf2[bc * NMODE + kx * 24 + ky0]     = make_float2(accC[0] + accS[1], accC[1] - accS[0]);
      Xf2[bc * NMODE + kx * 24 + ky0 + 1] = make_float2(accC[2] + accS[3], accC[3] - accS[2]);
    }
  } else {
    // ---- pointwise conv (XOR-swizzled LDS staging) ----
    f16 (*gt)[72] = (f16(*)[72])smem;
    f16 (*wt)[72] = (f16(*)[72])(smem + 36864);
    float* s_b    = (float*)(smem + 46080);
    int blk = blockIdx.x - 512;
    int b = blk >> 6, p0 = (blk & 63) * 256;
    for (int l = tid; l < 4096; l += 256) {
      int i = l >> 6, o = l & 63;
      wt[o][i ^ (((o >> 3) & 7) << 3)] = (f16)pww[l];
    }
    if (tid < 64) s_b[tid] = pwb[tid];
    for (int l = tid; l < 2048; l += 256) {
      int i = l >> 5, pc = (l & 31) * 8;
      f16x8 v = *(const f16x8*)(Gh + (size_t)(b * 64 + i) * HWC + p0 + pc);
      int sw = (l & 7) << 3;
#pragma unroll
      for (int j = 0; j < 8; ++j) gt[pc + j][i ^ sw] = v[j];
    }
    __syncthreads();
    int pw_ = wave * 64;
    f32x4 acc[4][4] = {};
#pragma unroll
    for (int kk = 0; kk < 2; ++kk) {
      f16x8 a[4], bb[4];
#pragma unroll
      for (int mi = 0; mi < 4; ++mi) {
        int o = 16 * mi + lr;
        a[mi] = *(const f16x8*)&wt[o][(kk * 32 + lg * 8) ^ (((o >> 3) & 7) << 3)];
      }
#pragma unroll
      for (int ni = 0; ni < 4; ++ni) {
        int p = pw_ + 16 * ni + lr;
        bb[ni] = *(const f16x8*)&gt[p][(kk * 32 + lg * 8) ^ (((p >> 3) & 7) << 3)];
      }
#pragma unroll
      for (int mi = 0; mi < 4; ++mi)
#pragma unroll
        for (int ni = 0; ni < 4; ++ni)
          acc[mi][ni] = __builtin_amdgcn_mfma_f32_16x16x32_f16(a[mi], bb[ni], acc[mi][ni], 0, 0, 0);
    }
    __syncthreads();
    f16 (*s_o)[264] = (f16(*)[264])smem;
#pragma unroll
    for (int mi = 0; mi < 4; ++mi)
#pragma unroll
      for (int ni = 0; ni < 4; ++ni) {
#pragma unroll
        for (int r = 0; r < 4; ++r) {
          int o = 16 * mi + lg * 4 + r;
          s_o[o][pw_ + 16 * ni + lr] = (f16)(acc[mi][ni][r] + s_b[o]);
        }
      }
    __syncthreads();
    for (int l = tid; l < 2048; l += 256) {
      int o = l >> 5, pc = (l & 31) * 8;
      *(f16x8*)(yh + (size_t)(b * 64 + o) * HWC + p0 + pc) = *(const f16x8*)&s_o[o][pc];
    }
  }
}

// ---------------- per-mode 64x64 complex channel mix ----------------
__global__ __launch_bounds__(128) void k_mix(const float2* __restrict__ Xf2,
    const float* __restrict__ w1r, const float* __restrict__ w1i,
    const float* __restrict__ w2r, const float* __restrict__ w2i,
    float2* __restrict__ Yf2)
{
  int m = blockIdx.x * 64 + (threadIdx.x & 63);
  int o = blockIdx.y * 2 + (threadIdx.x >> 6);
  int half = blockIdx.z;
  int gm = half * 576 + m;
  const float* wr_ = half ? w2r : w1r;
  const float* wi_ = half ? w2i : w1i;
  float aR[8] = {}, aI[8] = {};
#pragma unroll 2
  for (int i = 0; i < 64; ++i) {
    int widx = (i * 64 + o) * 576 + m;
    float wr = wr_[widx], wi = wi_[widx];
#pragma unroll
    for (int b = 0; b < 8; ++b) {
      float2 x = Xf2[(b * 64 + i) * NMODE + gm];
      aR[b] = fmaf(x.x, wr, aR[b]); aR[b] = fmaf(-x.y, wi, aR[b]);
      aI[b] = fmaf(x.x, wi, aI[b]); aI[b] = fmaf(x.y, wr, aI[b]);
    }
  }
#pragma unroll
  for (int b = 0; b < 8; ++b)
    Yf2[(b * 64 + o) * NMODE + gm] = make_float2(aR[b], aI[b]);
}

// ---------------- inverse DFT (two fused MFMA GEMMs) + add + instnorm + gelu ----------------
__global__ __launch_bounds__(256) void k_inv(const float2* __restrict__ Yf2,
                                             const f16* __restrict__ Bh_t, const f16* __restrict__ Bw_t,
                                             const f16* __restrict__ yh, f16* __restrict__ Gh)
{
  __shared__ f16 s_u[21120];
  __shared__ float rs[256], rq[256];
  __shared__ float s_mu, s_rstd;
  f16 (*s_a)[120]  = (f16(*)[120])s_u;
  f16 (*s_bh)[120] = (f16(*)[120])(s_u + 48 * 120);
  f16 (*s_t)[72]   = (f16(*)[72])s_u;
  f16 (*s_bw)[72]  = (f16(*)[72])(s_u + 128 * 72);
  f16 (*s_y)[136]  = (f16(*)[136])s_u;
  int bc = blockIdx.x, tid = threadIdx.x;

  for (int l = tid; l < 1152; l += 256) {
    int kx = l / 24, ky = l - kx * 24;
    float2 y = Yf2[bc * NMODE + l];
    s_a[2 * ky][kx]          = (f16)y.x;
    s_a[2 * ky][48 + kx]     = (f16)(-y.y);
    s_a[2 * ky + 1][kx]      = (f16)y.y;
    s_a[2 * ky + 1][48 + kx] = (f16)y.x;
  }
  for (int l = tid; l < 1536; l += 256) {
    int r = l / 12, c = l - r * 12;
    *(f16x8*)&s_bh[r][c * 8] = *(const f16x8*)(Bh_t + r * 96 + c * 8);
  }
  __syncthreads();
  int wave = tid >> 6, lane = tid & 63, lr = lane & 15, lg = lane >> 4;

  f32x4 acc_a[6];
#pragma unroll
  for (int i = 0; i < 6; ++i) acc_a[i] = (f32x4){0.f, 0.f, 0.f, 0.f};
#pragma unroll
  for (int i = 0; i < 6; ++i) {
    int t = wave + 4 * i;
    int mt = t >> 3, nt = t & 7;
#pragma unroll
    for (int ks = 0; ks < 3; ++ks) {
      f16x8 a = *(const f16x8*)&s_a[mt * 16 + lr][ks * 32 + lg * 8];
      f16x8 b = *(const f16x8*)&s_bh[nt * 16 + lr][ks * 32 + lg * 8];
      acc_a[i] = __builtin_amdgcn_mfma_f32_16x16x32_f16(a, b, acc_a[i], 0, 0, 0);
    }
  }
  __syncthreads();
#pragma unroll
  for (int i = 0; i < 6; ++i) {
    int t = wave + 4 * i;
    int mt = t >> 3, nt = t & 7;
    int h = nt * 16 + lr;
    int m0 = mt * 16 + lg * 4;
#pragma unroll
    for (int r = 0; r < 4; ++r) s_t[h][m0 + r] = (f16)acc_a[i][r];
  }
  for (int l = tid; l < 2048; l += 256) {
    int h = l >> 4, c = 48 + (l & 15);
    s_t[h][c] = (f16)0.f;
  }
  for (int l = tid; l < 1024; l += 256) {
    int r = l >> 3, c = l & 7;
    *(f16x8*)&s_bw[r][c * 8] = *(const f16x8*)(Bw_t + r * 64 + c * 8);
  }
  __syncthreads();

  f32x4 acc_b[2][8] = {};
#pragma unroll
  for (int ks = 0; ks < 2; ++ks) {
    f16x8 a[2], b[8];
#pragma unroll
    for (int mm = 0; mm < 2; ++mm) a[mm] = *(const f16x8*)&s_t[(wave * 2 + mm) * 16 + lr][ks * 32 + lg * 8];
#pragma unroll
    for (int nt = 0; nt < 8; ++nt) b[nt] = *(const f16x8*)&s_bw[nt * 16 + lr][ks * 32 + lg * 8];
#pragma unroll
    for (int mm = 0; mm < 2; ++mm)
#pragma unroll
      for (int nt = 0; nt < 8; ++nt)
        acc_b[mm][nt] = __builtin_amdgcn_mfma_f32_16x16x32_f16(a[mm], b[nt], acc_b[mm][nt], 0, 0, 0);
  }
  __syncthreads();
  for (int l = tid; l < 2048; l += 256) {
    int r = l >> 4, c = l & 15;
    *(f16x8*)&s_y[r][c * 8] = *(const f16x8*)(yh + (size_t)bc * HWC + r * 128 + c * 8);
  }
  __syncthreads();
  float sum = 0.f, ssq = 0.f;
#pragma unroll
  for (int mm = 0; mm < 2; ++mm)
#pragma unroll
    for (int nt = 0; nt < 8; ++nt)
#pragma unroll
      for (int r = 0; r < 4; ++r) {
        int h = (wave * 2 + mm) * 16 + lg * 4 + r;
        int w = nt * 16 + lr;
        float v = acc_b[mm][nt][r] * (1.f / 16384.f) + (float)s_y[h][w];
        acc_b[mm][nt][r] = v;
        sum += v; ssq = fmaf(v, v, ssq);
      }
  rs[tid] = sum; rq[tid] = ssq;
  __syncthreads();
  for (int sft = 128; sft > 0; sft >>= 1) {
    if (tid < sft) { rs[tid] += rs[tid + sft]; rq[tid] += rq[tid + sft]; }
    __syncthreads();
  }
  if (tid == 0) {
    float mu = rs[0] * (1.f / 16384.f);
    float var = fmaxf(rq[0] * (1.f / 16384.f) - mu * mu, 0.f);
    s_mu = mu;
    s_rstd = rsqrtf(var + 1e-5f);
  }
  __syncthreads();
  float mu = s_mu, rstd = s_rstd;
#pragma unroll
  for (int mm = 0; mm < 2; ++mm)
#pragma unroll
    for (int nt = 0; nt < 8; ++nt)
#pragma unroll
      for (int r = 0; r < 4; ++r) {
        int h = (wave * 2 + mm) * 16 + lg * 4 + r;
        int w = nt * 16 + lr;
        s_y[h][w] = (f16)gelu_f((acc_b[mm][nt][r] - mu) * rstd);
      }
  __syncthreads();
  for (int l = tid; l < 2048; l += 256) {
    int r = l >> 4, c = l & 15;
    *(f16x8*)(Gh + (size_t)bc * HWC + r * 128 + c * 8) = *(const f16x8*)&s_y[r][c * 8];
  }
}

// ---------------- transpose final grid ----------------
__global__ __launch_bounds__(256) void k_tr(const f16* __restrict__ Gh, f16* __restrict__ Gp)
{
  __shared__ f16 t[64][264];
  int b = blockIdx.x >> 6, cell0 = (blockIdx.x & 63) * 256, tid = threadIdx.x;
  for (int l = tid; l < 2048; l += 256) {
    int c = l >> 5, q = l & 31;
    *(f16x8*)&t[c][q * 8] = *(const f16x8*)(Gh + (size_t)(b * 64 + c) * HWC + cell0 + q * 8);
  }
  __syncthreads();
  int cell = tid;
  f16* dst = Gp + ((size_t)b * HWC + cell0 + cell) * 64;
#pragma unroll
  for (int q = 0; q < 8; ++q) {
    f16x8 v;
#pragma unroll
    for (int j = 0; j < 8; ++j) v[j] = t[q * 8 + j][cell];
    *(f16x8*)(dst + q * 8) = v;
  }
}

// ---------------- gather: 1 thread per (point, 8ch) -> max TLP ----------------
__global__ __launch_bounds__(256) void k_gather(const f16* __restrict__ Gp,
                                                const int4* __restrict__ pds,
                                                f16* __restrict__ smp)
{
  int idx = blockIdx.x * 256 + threadIdx.x;     // 0 .. 1048575
  int spt = idx >> 3, c8 = (idx & 7) * 8;
  int4 rec = pds[spt];
  int b = rec.x >> 14;
  int h0 = rec.y & 255, w0 = (rec.y >> 8) & 255;
  int h1 = min(h0 + 1, 127), w1 = min(w0 + 1, 127);
  float th = __int_as_float(rec.z), tw = __int_as_float(rec.w);
  float w00 = (1.f - th) * (1.f - tw), w01 = (1.f - th) * tw;
  float w10 = th * (1.f - tw), w11 = th * tw;
  const f16* base = Gp + (((size_t)b << 14) << 6);
  f16x8 a  = *(const f16x8*)(base + (h0 * 128 + w0) * 64 + c8);
  f16x8 b2 = *(const f16x8*)(base + (h0 * 128 + w1) * 64 + c8);
  f16x8 c  = *(const f16x8*)(base + (h1 * 128 + w0) * 64 + c8);
  f16x8 d  = *(const f16x8*)(base + (h1 * 128 + w1) * 64 + c8);
  f16x8 o;
#pragma unroll
  for (int j = 0; j < 8; ++j)
    o[j] = (f16)(w00 * (float)a[j] + w01 * (float)b2[j] + w10 * (float)c[j] + w11 * (float)d[j]);
  *(f16x8*)(smp + (size_t)spt * 64 + c8) = o;
}

// ---------------- dense projection MLP via MFMA (sequential smp reads) ----------------
__global__ __launch_bounds__(256) void k_mlp(const f16* __restrict__ smp,
                                             const int4* __restrict__ pds,
                                             const f16* __restrict__ p1t,
                                             const float* __restrict__ p1b,
                                             const float* __restrict__ p2w, const float* __restrict__ p2b,
                                             float* __restrict__ out)
{
  __shared__ f16 s_in[128][72];
  __shared__ f16 s_p1[128][72];
  __shared__ float s_b1[128], s_p2[128];
  int blk = blockIdx.x, tid = threadIdx.x;
  for (int l = tid; l < 1024; l += 256) {
    int row = l >> 3, c8 = (l & 7) * 8;
    *(f16x8*)&s_in[row][c8] = *(const f16x8*)(smp + ((size_t)blk * 128 + row) * 64 + c8);
  }
  for (int l = tid; l < 1024; l += 256) {
    int j = l >> 3, c8 = (l & 7) * 8;
    *(f16x8*)&s_p1[j][c8] = *(const f16x8*)(p1t + j * 64 + c8);
  }
  if (tid < 128) { s_b1[tid] = p1b[tid]; s_p2[tid] = p2w[tid]; }
  __syncthreads();
  int wave = tid >> 6, lane = tid & 63, lr = lane & 15, lg = lane >> 4;
  f32x4 acc[2][8] = {};
#pragma unroll
  for (int ks = 0; ks < 2; ++ks) {
    f16x8 a[2], b[8];
#pragma unroll
    for (int mm = 0; mm < 2; ++mm) a[mm] = *(const f16x8*)&s_in[(wave * 2 + mm) * 16 + lr][ks * 32 + lg * 8];
#pragma unroll
    for (int nt = 0; nt < 8; ++nt) b[nt] = *(const f16x8*)&s_p1[nt * 16 + lr][ks * 32 + lg * 8];
#pragma unroll
    for (int mm = 0; mm < 2; ++mm)
#pragma unroll
      for (int nt = 0; nt < 8; ++nt)
        acc[mm][nt] = __builtin_amdgcn_mfma_f32_16x16x32_f16(a[mm], b[nt], acc[mm][nt], 0, 0, 0);
  }
  float p2b0 = p2b[0];
  float part[2][4] = {};
#pragma unroll
  for (int mm = 0; mm < 2; ++mm)
#pragma unroll
    for (int nt = 0; nt < 8; ++nt) {
#pragma unroll
      for (int r = 0; r < 4; ++r) {
        int j = nt * 16 + lr;
        part[mm][r] += gelu_f(acc[mm][nt][r] + s_b1[j]) * s_p2[j];
      }
    }
#pragma unroll
  for (int mm = 0; mm < 2; ++mm)
#pragma unroll
    for (int r = 0; r < 4; ++r) {
      float v = part[mm][r];
      v += __shfl_xor(v, 1, 16);
      v += __shfl_xor(v, 2, 16);
      v += __shfl_xor(v, 4, 16);
      v += __shfl_xor(v, 8, 16);
      if (lr == 0) {
        int pt = (wave * 2 + mm) * 16 + lg * 4 + r;
        int opid = pds[blk * 128 + pt].x;
        out[opid] = v + p2b0;
      }
    }
}

extern "C" void kernel_launch(void* const* d_in, const int* in_sizes, int n_in,
                              void* d_out, int out_size, void* d_ws, size_t ws_size,
                              hipStream_t stream) {
  const float* coords = (const float*)d_in[0];
  const float* feats  = (const float*)d_in[1];
  const float* dw0 = (const float*)d_in[2];
  const float* db0 = (const float*)d_in[3];
  const float* dw1 = (const float*)d_in[4];
  const float* db1 = (const float*)d_in[5];
  const float* dw2 = (const float*)d_in[6];
  const float* db2 = (const float*)d_in[7];
  const float* liftw = (const float*)d_in[8];
  const float* liftb = (const float*)d_in[9];
  const float* sw1r = (const float*)d_in[10];
  const float* sw1i = (const float*)d_in[11];
  const float* sw2r = (const float*)d_in[12];
  const float* sw2i = (const float*)d_in[13];
  const float* pww = (const float*)d_in[14];
  const float* pwb = (const float*)d_in[15];
  const float* p1w = (const float*)d_in[16];
  const float* p1b = (const float*)d_in[17];
  const float* p2w = (const float*)d_in[18];
  const float* p2b = (const float*)d_in[19];
  float* out = (float*)d_out;
  char* base = (char*)d_ws;

  int*    cnt_i  = (int*)(base + 0);
  int*    ptrank = (int*)(base + 524288);
  int*    pd_cell= (int*)(base + 1048576);
  int*    starts = (int*)(base + 1572864);
  int*    btot   = (int*)(base + 2097152);
  int*    boff   = (int*)(base + 2098176);
  int*    pd_idx = (int*)(base + 2099200);
  float*  pd_th  = (float*)(base + 2623488);
  float*  pd_tw  = (float*)(base + 3147776);
  f16*    Gh     = (f16*)(base + 8388608);
  f16*    yh     = (f16*)(base + 25165824);
  f16*    smp    = (f16*)(base + 25165824);   // alias: yh dead after last k_inv
  float2* Xf2    = (float2*)(base + 41943040);
  float2* Yf2    = (float2*)(base + 46661632);
  int4*   pds    = (int4*)(base + 51380224);
  f16*    Gp     = (f16*)(base + 53477376);
  float4* scA    = (float4*)(base + 70254592);
  float*  scB    = (float*)(base + 72351744);
  f16*    Fw_t   = (f16*)(base + 87031808);
  f16*    Fh_t   = (f16*)(base + 87044096);
  f16*    Bh_t   = (f16*)(base + 87068672);
  f16*    Bw_t   = (f16*)(base + 87093248);
  f16*    p1t    = (f16*)(base + 87109632);

  hipMemsetAsync(cnt_i, 0, 524288, stream);

  k_twiddle<<<136, 256, 0, stream>>>(Fw_t, Fh_t, Bh_t, Bw_t, p1w, p1t);
  k_points<<<512, 256, 0, stream>>>(coords, dw0, db0, dw1, db1, dw2, db2,
                                    cnt_i, ptrank, pd_cell, pd_idx, pd_th, pd_tw);
  k_scanA<<<256, 256, 0, stream>>>(cnt_i, starts, btot);
  k_scanB<<<1, 256, 0, stream>>>(btot, boff);
  k_perm<<<512, 256, 0, stream>>>(pd_cell, ptrank, starts, boff, pd_idx, pd_th, pd_tw,
                                  coords, feats, pds, scA, scB);
  k_gridlift<<<dim3(128, 8), 256, 0, stream>>>(scA, scB, starts, boff, cnt_i, liftw, liftb, Gh);

  for (int d = 0; d < 4; ++d) {
    const int swoff = d * 2359296;
    k_fwdpw<<<1024, 256, 0, stream>>>(Gh, Fw_t, Fh_t, Xf2, pww + d * 4096, pwb + d * 64, yh);
    k_mix<<<dim3(9, 32, 2), 128, 0, stream>>>(Xf2, sw1r + swoff, sw1i + swoff,
                                              sw2r + swoff, sw2i + swoff, Yf2);
    k_inv<<<512, 256, 0, stream>>>(Yf2, Bh_t, Bw_t, yh, Gh);
  }

  k_tr<<<512, 256, 0, stream>>>(Gh, Gp);
  k_gather<<<4096, 256, 0, stream>>>(Gp, pds, smp);
  k_mlp<<<1024, 256, 0, stream>>>(smp, pds, p1t, p1b, p2w, p2b, out);
}

// Round 13
// 351.660 us; speedup vs baseline: 1.1070x; 1.1070x over previous
//
#include <hip/hip_runtime.h>
#include <math.h>

#define GH 128
#define GW 128
#define HWC 16384
#define NMODE 1152
#define PI_F 3.14159265358979323846f

typedef _Float16 f16;
typedef __attribute__((ext_vector_type(8))) _Float16 f16x8;
typedef __attribute__((ext_vector_type(4))) float f32x4;

// exact-path gelu (k_points only: feeds cell rounding, keep bit-compatible)
__device__ __forceinline__ float gelu_f(float x) {
  return 0.5f * x * (1.0f + erff(x * 0.70710678118654752f));
}

// fast gelu: A&S 7.1.26 erf (max abs err 1.5e-7), __expf -> v_exp_f32
__device__ __forceinline__ float gelu_fast(float x) {
  float ax = fabsf(x) * 0.70710678118654752f;
  float t = 1.f / fmaf(0.3275911f, ax, 1.f);
  float p = t * fmaf(t, fmaf(t, fmaf(t, fmaf(t, 1.061405429f, -1.453152027f),
                                     1.421413741f), -0.284496736f), 0.254829592f);
  float e = __expf(-ax * ax);
  float r = 1.f - p * e;                 // erf(|x|/sqrt2)
  r = copysignf(r, x);
  return 0.5f * x * (1.f + r);
}

// ---------------- prep: twiddle tables + f16-transposed p1 ----------------
__global__ __launch_bounds__(256) void k_twiddle(f16* __restrict__ Fw, f16* __restrict__ Fh,
                                                 f16* __restrict__ Bh, f16* __restrict__ Bw,
                                                 const float* __restrict__ p1w, f16* __restrict__ p1t)
{
  int idx = blockIdx.x * 256 + threadIdx.x;
  if (idx < 6144) {
    int n = idx >> 7, w = idx & 127;
    int ky = n >> 1;
    int ang = (ky * w) & 127;
    float s, c; sincosf((float)ang * (PI_F / 64.f), &s, &c);
    Fw[idx] = (f16)((n & 1) ? -s : c);
  } else if (idx < 18432) {
    int t = idx - 6144;
    int n = t >> 7, h = t & 127;
    int kx = n < 48 ? n : n - 48;
    int f = kx < 24 ? kx : kx + 80;
    int ang = (f * h) & 127;
    float s, c; sincosf((float)ang * (PI_F / 64.f), &s, &c);
    float v = (n < 48) ? c : s;
    Fh[t] = (f16)v;
    Bh[h * 96 + n] = (f16)v;
  } else if (idx < 26624) {
    int t = idx - 18432;
    int w = t >> 6, k = t & 63;
    float v = 0.f;
    if (k < 48 && k != 1) {
      int ky = k >> 1;
      float g = (ky == 0) ? 1.f : 2.f;
      int ang = (ky * w) & 127;
      float s, c; sincosf((float)ang * (PI_F / 64.f), &s, &c);
      v = (k & 1) ? -g * s : g * c;
    }
    Bw[t] = (f16)v;
  } else if (idx < 34816) {
    int t = idx - 26624;          // t = j*64 + i
    int j = t >> 6, i = t & 63;
    p1t[t] = (f16)p1w[i * 128 + j];
  }
}

// ---------------- points: deform MLP (f32, exact erf) + rank atomic + bilinear data ----------------
__global__ __launch_bounds__(256) void k_points(
    const float* __restrict__ coords,
    const float* __restrict__ dw0, const float* __restrict__ db0,
    const float* __restrict__ dw1, const float* __restrict__ db1,
    const float* __restrict__ dw2, const float* __restrict__ db2,
    int* __restrict__ cnt_i,
    int* __restrict__ ptrank, int* __restrict__ pd_cell,
    int* __restrict__ pd_idx, float* __restrict__ pd_th, float* __restrict__ pd_tw)
{
  int pid = blockIdx.x * 256 + threadIdx.x;
  float2 c = ((const float2*)coords)[pid];

  float h1[32];
#pragma unroll
  for (int j = 0; j < 32; ++j)
    h1[j] = gelu_f(fmaf(c.x, dw0[j], fmaf(c.y, dw0[32 + j], db0[j])));

  float a[32];
#pragma unroll
  for (int j = 0; j < 32; ++j) a[j] = db1[j];
#pragma unroll 4
  for (int k = 0; k < 32; ++k) {
    float hk = h1[k];
    const float* wr = dw1 + k * 32;
#pragma unroll
    for (int j = 0; j < 32; ++j) a[j] = fmaf(hk, wr[j], a[j]);
  }

  float d0 = db2[0], d1 = db2[1];
#pragma unroll 4
  for (int k = 0; k < 32; ++k) {
    float hk = gelu_f(a[k]);
    d0 = fmaf(hk, dw2[2 * k], d0);
    d1 = fmaf(hk, dw2[2 * k + 1], d1);
  }

  float l0 = fminf(fmaxf(c.x + d0, -1.f), 1.f);
  float l1 = fminf(fmaxf(c.y + d1, -1.f), 1.f);
  float ph = (l0 + 1.f) * 0.5f * 127.f;
  float pw = (l1 + 1.f) * 0.5f * 127.f;
  int ih = min(max((int)rintf(ph), 0), 127);
  int iw = min(max((int)rintf(pw), 0), 127);
  int b = pid >> 14;
  int cell = b * HWC + ih * GW + iw;

  int r = atomicAdd(&cnt_i[cell], 1);
  ptrank[pid] = r;
  pd_cell[pid] = cell;

  float fh = floorf(ph), fw = floorf(pw);
  int h0i = min(max((int)fh, 0), 127), w0i = min(max((int)fw, 0), 127);
  pd_idx[pid] = h0i | (w0i << 8);
  pd_th[pid] = ph - fh;
  pd_tw[pid] = pw - fw;
}

// ---------------- scans ----------------
__global__ __launch_bounds__(256) void k_scanA(const int* __restrict__ cnt,
                                               int* __restrict__ starts, int* __restrict__ btot)
{
  __shared__ int sh[256];
  int blk = blockIdx.x, t = threadIdx.x;
  int base = blk * 512;
  int v0 = cnt[base + 2 * t], v1 = cnt[base + 2 * t + 1];
  int pair = v0 + v1;
  sh[t] = pair; __syncthreads();
  int acc = pair;
  for (int off = 1; off < 256; off <<= 1) {
    int add = (t >= off) ? sh[t - off] : 0;
    __syncthreads();
    acc += add; sh[t] = acc;
    __syncthreads();
  }
  int excl = acc - pair;
  starts[base + 2 * t] = excl;
  starts[base + 2 * t + 1] = excl + v0;
  if (t == 255) btot[blk] = acc;
}

__global__ __launch_bounds__(256) void k_scanB(const int* __restrict__ btot, int* __restrict__ boff)
{
  __shared__ int sh[256];
  int t = threadIdx.x;
  int v = btot[t];
  sh[t] = v; __syncthreads();
  int acc = v;
  for (int off = 1; off < 256; off <<= 1) {
    int add = (t >= off) ? sh[t - off] : 0;
    __syncthreads();
    acc += add; sh[t] = acc;
    __syncthreads();
  }
  boff[t] = acc - v;
}

// ---------------- permute ----------------
__global__ __launch_bounds__(256) void k_perm(const int* __restrict__ pd_cell, const int* __restrict__ ptrank,
                                              const int* __restrict__ starts, const int* __restrict__ boff,
                                              const int* __restrict__ pd_idx, const float* __restrict__ pd_th,
                                              const float* __restrict__ pd_tw,
                                              const float* __restrict__ coords, const float* __restrict__ feats,
                                              int4* __restrict__ pds,
                                              float4* __restrict__ scA, float* __restrict__ scB)
{
  int pid = blockIdx.x * 256 + threadIdx.x;
  int cell = pd_cell[pid];
  int dst = starts[cell] + boff[cell >> 9] + ptrank[pid];
  int4 rec;
  rec.x = pid;
  rec.y = pd_idx[pid];
  rec.z = __float_as_int(pd_th[pid]);
  rec.w = __float_as_int(pd_tw[pid]);
  pds[dst] = rec;
  float2 c = ((const float2*)coords)[pid];
  scA[dst] = make_float4(feats[pid * 3], feats[pid * 3 + 1], feats[pid * 3 + 2], c.x);
  scB[dst] = c.y;
}

// ---------------- segmented cell-sum + lift -> Gh (f16) ----------------
__global__ __launch_bounds__(256) void k_gridlift(const float4* __restrict__ scA, const float* __restrict__ scB,
                                                  const int* __restrict__ starts, const int* __restrict__ boff,
                                                  const int* __restrict__ cnt_i,
                                                  const float* __restrict__ lw,
                                                  const float* __restrict__ lb,
                                                  f16* __restrict__ Gh)
{
  __shared__ float sp[2][128][5];
  __shared__ float s_lw[5][64];
  __shared__ float s_lb[64];
  __shared__ float s_cnt[128];
  int b = blockIdx.y, cbase = blockIdx.x * 128, tid = threadIdx.x;
  int cl = tid & 127, par = tid >> 7;
  int gcell = b * HWC + cbase + cl;
  int start = starts[gcell] + boff[gcell >> 9];
  int cnt = cnt_i[gcell];
  float a0 = 0.f, a1 = 0.f, a2 = 0.f, a3 = 0.f, a4 = 0.f;
  for (int p = start + par; p < start + cnt; p += 2) {
    float4 A = scA[p];
    a0 += A.x; a1 += A.y; a2 += A.z; a3 += A.w; a4 += scB[p];
  }
  sp[par][cl][0] = a0; sp[par][cl][1] = a1; sp[par][cl][2] = a2;
  sp[par][cl][3] = a3; sp[par][cl][4] = a4;
  if (par == 0) s_cnt[cl] = (float)cnt;
  for (int l = tid; l < 320; l += 256) ((float*)s_lw)[l] = lw[l];
  if (tid < 64) s_lb[tid] = lb[tid];
  __syncthreads();
  float v0 = sp[0][cl][0] + sp[1][cl][0];
  float v1 = sp[0][cl][1] + sp[1][cl][1];
  float v2 = sp[0][cl][2] + sp[1][cl][2];
  float v3 = sp[0][cl][3] + sp[1][cl][3];
  float v4 = sp[0][cl][4] + sp[1][cl][4];
  float cntf = s_cnt[cl];
  float inv = 1.f / fmaxf(cntf, 1.f);
  int oh = tid >> 7;
#pragma unroll
  for (int j = 0; j < 32; ++j) {
    int o = oh * 32 + j;
    float val = cntf * s_lb[o];
    val = fmaf(v0, s_lw[0][o], val);
    val = fmaf(v1, s_lw[1][o], val);
    val = fmaf(v2, s_lw[2][o], val);
    val = fmaf(v3, s_lw[3][o], val);
    val = fmaf(v4, s_lw[4][o], val);
    Gh[(size_t)(b * 64 + o) * HWC + cbase + cl] = (f16)(val * inv);
  }
}

// ---------------- fused forward DFT (blocks 0..511) + pointwise conv (blocks 512..1023) ----------------
__global__ __launch_bounds__(256) void k_fwdpw(const f16* __restrict__ Gh,
                                               const f16* __restrict__ Fw_t, const f16* __restrict__ Fh_t,
                                               float2* __restrict__ Xf2,
                                               const float* __restrict__ pww, const float* __restrict__ pwb,
                                               f16* __restrict__ yh)
{
  __shared__ char smem[52224];
  int tid = threadIdx.x;
  int wave = tid >> 6, lane = tid & 63, lr = lane & 15, lg = lane >> 4;

  if (blockIdx.x < 512) {
    // ---- forward DFT ----
    f16 (*s_fw)[136]  = (f16(*)[136])smem;
    f16 (*s_img)[136] = (f16(*)[136])(smem + 13056);
    f16 (*s_xw)[136]  = (f16(*)[136])(smem + 13056);
    f16 (*s_fh)[136]  = (f16(*)[136])(smem + 13056 + 48 * 136 * 2);
    int bc = blockIdx.x;
    for (int l = tid; l < 2048; l += 256) {
      int r = l >> 4, c = l & 15;
      *(f16x8*)&s_img[r][c * 8] = *(const f16x8*)(Gh + (size_t)bc * HWC + r * 128 + c * 8);
    }
    for (int l = tid; l < 768; l += 256) {
      int r = l >> 4, c = l & 15;
      *(f16x8*)&s_fw[r][c * 8] = *(const f16x8*)(Fw_t + r * 128 + c * 8);
    }
    __syncthreads();

    f32x4 acc1[2][3] = {};
#pragma unroll
    for (int ks = 0; ks < 4; ++ks) {
      f16x8 a[2], b[3];
#pragma unroll
      for (int mm = 0; mm < 2; ++mm) a[mm] = *(const f16x8*)&s_img[(wave * 2 + mm) * 16 + lr][ks * 32 + lg * 8];
#pragma unroll
      for (int nt = 0; nt < 3; ++nt) b[nt] = *(const f16x8*)&s_fw[nt * 16 + lr][ks * 32 + lg * 8];
#pragma unroll
      for (int mm = 0; mm < 2; ++mm)
#pragma unroll
        for (int nt = 0; nt < 3; ++nt)
          acc1[mm][nt] = __builtin_amdgcn_mfma_f32_16x16x32_f16(a[mm], b[nt], acc1[mm][nt], 0, 0, 0);
    }
    __syncthreads();
#pragma unroll
    for (int mm = 0; mm < 2; ++mm)
#pragma unroll
      for (int nt = 0; nt < 3; ++nt) {
        int n = nt * 16 + lr;
        int h0 = (wave * 2 + mm) * 16 + lg * 4;
#pragma unroll
        for (int r = 0; r < 4; ++r) s_xw[n][h0 + r] = (f16)acc1[mm][nt][r];
      }
    for (int l = tid; l < 1536; l += 256) {
      int r = l >> 4, c = l & 15;
      *(f16x8*)&s_fh[r][c * 8] = *(const f16x8*)(Fh_t + r * 128 + c * 8);
    }
    __syncthreads();

    for (int u = wave; u < 9; u += 4) {
      int mt = u / 3, ntC = u - mt * 3;
      f32x4 accC = {}, accS = {};
#pragma unroll
      for (int ks = 0; ks < 4; ++ks) {
        f16x8 a  = *(const f16x8*)&s_xw[mt * 16 + lr][ks * 32 + lg * 8];
        f16x8 bC = *(const f16x8*)&s_fh[ntC * 16 + lr][ks * 32 + lg * 8];
        f16x8 bS = *(const f16x8*)&s_fh[(ntC + 3) * 16 + lr][ks * 32 + lg * 8];
        accC = __builtin_amdgcn_mfma_f32_16x16x32_f16(a, bC, accC, 0, 0, 0);
        accS = __builtin_amdgcn_mfma_f32_16x16x32_f16(a, bS, accS, 0, 0, 0);
      }
      int kx = ntC * 16 + lr;
      int ky0 = (mt * 16 + lg * 4) >> 1;
      Xf2[bc * NMODE + kx * 24 + ky0]     = make_float2(accC[0] + accS[1], accC[1] - accS[0]);
      Xf2[bc * NMODE + kx * 24 + ky0 + 1] = make_float2(accC[2] + accS[3], accC[3] - accS[2]);
    }
  } else {
    // ---- pointwise conv (XOR-swizzled LDS staging) ----
    f16 (*gt)[72] = (f16(*)[72])smem;
    f16 (*wt)[72] = (f16(*)[72])(smem + 36864);
    float* s_b    = (float*)(smem + 46080);
    int blk = blockIdx.x - 512;
    int b = blk >> 6, p0 = (blk & 63) * 256;
    for (int l = tid; l < 4096; l += 256) {
      int i = l >> 6, o = l & 63;
      wt[o][i ^ (((o >> 3) & 7) << 3)] = (f16)pww[l];
    }
    if (tid < 64) s_b[tid] = pwb[tid];
    for (int l = tid; l < 2048; l += 256) {
      int i = l >> 5, pc = (l & 31) * 8;
      f16x8 v = *(const f16x8*)(Gh + (size_t)(b * 64 + i) * HWC + p0 + pc);
      int sw = (l & 7) << 3;
#pragma unroll
      for (int j = 0; j < 8; ++j) gt[pc + j][i ^ sw] = v[j];
    }
    __syncthreads();
    int pw_ = wave * 64;
    f32x4 acc[4][4] = {};
#pragma unroll
    for (int kk = 0; kk < 2; ++kk) {
      f16x8 a[4], bb[4];
#pragma unroll
      for (int mi = 0; mi < 4; ++mi) {
        int o = 16 * mi + lr;
        a[mi] = *(const f16x8*)&wt[o][(kk * 32 + lg * 8) ^ (((o >> 3) & 7) << 3)];
      }
#pragma unroll
      for (int ni = 0; ni < 4; ++ni) {
        int p = pw_ + 16 * ni + lr;
        bb[ni] = *(const f16x8*)&gt[p][(kk * 32 + lg * 8) ^ (((p >> 3) & 7) << 3)];
      }
#pragma unroll
      for (int mi = 0; mi < 4; ++mi)
#pragma unroll
        for (int ni = 0; ni < 4; ++ni)
          acc[mi][ni] = __builtin_amdgcn_mfma_f32_16x16x32_f16(a[mi], bb[ni], acc[mi][ni], 0, 0, 0);
    }
    __syncthreads();
    f16 (*s_o)[264] = (f16(*)[264])smem;
#pragma unroll
    for (int mi = 0; mi < 4; ++mi)
#pragma unroll
      for (int ni = 0; ni < 4; ++ni) {
#pragma unroll
        for (int r = 0; r < 4; ++r) {
          int o = 16 * mi + lg * 4 + r;
          s_o[o][pw_ + 16 * ni + lr] = (f16)(acc[mi][ni][r] + s_b[o]);
        }
      }
    __syncthreads();
    for (int l = tid; l < 2048; l += 256) {
      int o = l >> 5, pc = (l & 31) * 8;
      *(f16x8*)(yh + (size_t)(b * 64 + o) * HWC + p0 + pc) = *(const f16x8*)&s_o[o][pc];
    }
  }
}

// ---------------- per-mode 64x64 complex channel mix (deep unroll for load ILP) ----------------
__global__ __launch_bounds__(128) void k_mix(const float2* __restrict__ Xf2,
    const float* __restrict__ w1r, const float* __restrict__ w1i,
    const float* __restrict__ w2r, const float* __restrict__ w2i,
    float2* __restrict__ Yf2)
{
  int m = blockIdx.x * 64 + (threadIdx.x & 63);
  int o = blockIdx.y * 2 + (threadIdx.x >> 6);
  int half = blockIdx.z;
  int gm = half * 576 + m;
  const float* wr_ = half ? w2r : w1r;
  const float* wi_ = half ? w2i : w1i;
  float aR[8] = {}, aI[8] = {};
#pragma unroll 4
  for (int i = 0; i < 64; ++i) {
    int widx = (i * 64 + o) * 576 + m;
    float wr = wr_[widx], wi = wi_[widx];
#pragma unroll
    for (int b = 0; b < 8; ++b) {
      float2 x = Xf2[(b * 64 + i) * NMODE + gm];
      aR[b] = fmaf(x.x, wr, aR[b]); aR[b] = fmaf(-x.y, wi, aR[b]);
      aI[b] = fmaf(x.x, wi, aI[b]); aI[b] = fmaf(x.y, wr, aI[b]);
    }
  }
#pragma unroll
  for (int b = 0; b < 8; ++b)
    Yf2[(b * 64 + o) * NMODE + gm] = make_float2(aR[b], aI[b]);
}

// ---------------- inverse DFT (two fused MFMA GEMMs) + add + instnorm + gelu ----------------
__global__ __launch_bounds__(256) void k_inv(const float2* __restrict__ Yf2,
                                             const f16* __restrict__ Bh_t, const f16* __restrict__ Bw_t,
                                             const f16* __restrict__ yh, f16* __restrict__ Gh)
{
  __shared__ f16 s_u[21120];
  __shared__ float rs[256], rq[256];
  __shared__ float s_mu, s_rstd;
  f16 (*s_a)[120]  = (f16(*)[120])s_u;
  f16 (*s_bh)[120] = (f16(*)[120])(s_u + 48 * 120);
  f16 (*s_t)[72]   = (f16(*)[72])s_u;
  f16 (*s_bw)[72]  = (f16(*)[72])(s_u + 128 * 72);
  f16 (*s_y)[136]  = (f16(*)[136])s_u;
  int bc = blockIdx.x, tid = threadIdx.x;

  for (int l = tid; l < 1152; l += 256) {
    int kx = l / 24, ky = l - kx * 24;
    float2 y = Yf2[bc * NMODE + l];
    s_a[2 * ky][kx]          = (f16)y.x;
    s_a[2 * ky][48 + kx]     = (f16)(-y.y);
    s_a[2 * ky + 1][kx]      = (f16)y.y;
    s_a[2 * ky + 1][48 + kx] = (f16)y.x;
  }
  for (int l = tid; l < 1536; l += 256) {
    int r = l / 12, c = l - r * 12;
    *(f16x8*)&s_bh[r][c * 8] = *(const f16x8*)(Bh_t + r * 96 + c * 8);
  }
  __syncthreads();
  int wave = tid >> 6, lane = tid & 63, lr = lane & 15, lg = lane >> 4;

  f32x4 acc_a[6];
#pragma unroll
  for (int i = 0; i < 6; ++i) acc_a[i] = (f32x4){0.f, 0.f, 0.f, 0.f};
#pragma unroll
  for (int i = 0; i < 6; ++i) {
    int t = wave + 4 * i;
    int mt = t >> 3, nt = t & 7;
#pragma unroll
    for (int ks = 0; ks < 3; ++ks) {
      f16x8 a = *(const f16x8*)&s_a[mt * 16 + lr][ks * 32 + lg * 8];
      f16x8 b = *(const f16x8*)&s_bh[nt * 16 + lr][ks * 32 + lg * 8];
      acc_a[i] = __builtin_amdgcn_mfma_f32_16x16x32_f16(a, b, acc_a[i], 0, 0, 0);
    }
  }
  __syncthreads();
#pragma unroll
  for (int i = 0; i < 6; ++i) {
    int t = wave + 4 * i;
    int mt = t >> 3, nt = t & 7;
    int h = nt * 16 + lr;
    int m0 = mt * 16 + lg * 4;
#pragma unroll
    for (int r = 0; r < 4; ++r) s_t[h][m0 + r] = (f16)acc_a[i][r];
  }
  for (int l = tid; l < 2048; l += 256) {
    int h = l >> 4, c = 48 + (l & 15);
    s_t[h][c] = (f16)0.f;
  }
  for (int l = tid; l < 1024; l += 256) {
    int r = l >> 3, c = l & 7;
    *(f16x8*)&s_bw[r][c * 8] = *(const f16x8*)(Bw_t + r * 64 + c * 8);
  }
  __syncthreads();

  f32x4 acc_b[2][8] = {};
#pragma unroll
  for (int ks = 0; ks < 2; ++ks) {
    f16x8 a[2], b[8];
#pragma unroll
    for (int mm = 0; mm < 2; ++mm) a[mm] = *(const f16x8*)&s_t[(wave * 2 + mm) * 16 + lr][ks * 32 + lg * 8];
#pragma unroll
    for (int nt = 0; nt < 8; ++nt) b[nt] = *(const f16x8*)&s_bw[nt * 16 + lr][ks * 32 + lg * 8];
#pragma unroll
    for (int mm = 0; mm < 2; ++mm)
#pragma unroll
      for (int nt = 0; nt < 8; ++nt)
        acc_b[mm][nt] = __builtin_amdgcn_mfma_f32_16x16x32_f16(a[mm], b[nt], acc_b[mm][nt], 0, 0, 0);
  }
  __syncthreads();
  for (int l = tid; l < 2048; l += 256) {
    int r = l >> 4, c = l & 15;
    *(f16x8*)&s_y[r][c * 8] = *(const f16x8*)(yh + (size_t)bc * HWC + r * 128 + c * 8);
  }
  __syncthreads();
  float sum = 0.f, ssq = 0.f;
#pragma unroll
  for (int mm = 0; mm < 2; ++mm)
#pragma unroll
    for (int nt = 0; nt < 8; ++nt)
#pragma unroll
      for (int r = 0; r < 4; ++r) {
        int h = (wave * 2 + mm) * 16 + lg * 4 + r;
        int w = nt * 16 + lr;
        float v = acc_b[mm][nt][r] * (1.f / 16384.f) + (float)s_y[h][w];
        acc_b[mm][nt][r] = v;
        sum += v; ssq = fmaf(v, v, ssq);
      }
  rs[tid] = sum; rq[tid] = ssq;
  __syncthreads();
  for (int sft = 128; sft > 0; sft >>= 1) {
    if (tid < sft) { rs[tid] += rs[tid + sft]; rq[tid] += rq[tid + sft]; }
    __syncthreads();
  }
  if (tid == 0) {
    float mu = rs[0] * (1.f / 16384.f);
    float var = fmaxf(rq[0] * (1.f / 16384.f) - mu * mu, 0.f);
    s_mu = mu;
    s_rstd = rsqrtf(var + 1e-5f);
  }
  __syncthreads();
  float mu = s_mu, rstd = s_rstd;
#pragma unroll
  for (int mm = 0; mm < 2; ++mm)
#pragma unroll
    for (int nt = 0; nt < 8; ++nt)
#pragma unroll
      for (int r = 0; r < 4; ++r) {
        int h = (wave * 2 + mm) * 16 + lg * 4 + r;
        int w = nt * 16 + lr;
        s_y[h][w] = (f16)gelu_fast((acc_b[mm][nt][r] - mu) * rstd);
      }
  __syncthreads();
  for (int l = tid; l < 2048; l += 256) {
    int r = l >> 4, c = l & 15;
    *(f16x8*)(Gh + (size_t)bc * HWC + r * 128 + c * 8) = *(const f16x8*)&s_y[r][c * 8];
  }
}

// ---------------- transpose final grid ----------------
__global__ __launch_bounds__(256) void k_tr(const f16* __restrict__ Gh, f16* __restrict__ Gp)
{
  __shared__ f16 t[64][264];
  int b = blockIdx.x >> 6, cell0 = (blockIdx.x & 63) * 256, tid = threadIdx.x;
  for (int l = tid; l < 2048; l += 256) {
    int c = l >> 5, q = l & 31;
    *(f16x8*)&t[c][q * 8] = *(const f16x8*)(Gh + (size_t)(b * 64 + c) * HWC + cell0 + q * 8);
  }
  __syncthreads();
  int cell = tid;
  f16* dst = Gp + ((size_t)b * HWC + cell0 + cell) * 64;
#pragma unroll
  for (int q = 0; q < 8; ++q) {
    f16x8 v;
#pragma unroll
    for (int j = 0; j < 8; ++j) v[j] = t[q * 8 + j][cell];
    *(f16x8*)(dst + q * 8) = v;
  }
}

// ---------------- gather: 1 thread per (point, 8ch) ----------------
__global__ __launch_bounds__(256) void k_gather(const f16* __restrict__ Gp,
                                                const int4* __restrict__ pds,
                                                f16* __restrict__ smp)
{
  int idx = blockIdx.x * 256 + threadIdx.x;
  int spt = idx >> 3, c8 = (idx & 7) * 8;
  int4 rec = pds[spt];
  int b = rec.x >> 14;
  int h0 = rec.y & 255, w0 = (rec.y >> 8) & 255;
  int h1 = min(h0 + 1, 127), w1 = min(w0 + 1, 127);
  float th = __int_as_float(rec.z), tw = __int_as_float(rec.w);
  float w00 = (1.f - th) * (1.f - tw), w01 = (1.f - th) * tw;
  float w10 = th * (1.f - tw), w11 = th * tw;
  const f16* base = Gp + (((size_t)b << 14) << 6);
  f16x8 a  = *(const f16x8*)(base + (h0 * 128 + w0) * 64 + c8);
  f16x8 b2 = *(const f16x8*)(base + (h0 * 128 + w1) * 64 + c8);
  f16x8 c  = *(const f16x8*)(base + (h1 * 128 + w0) * 64 + c8);
  f16x8 d  = *(const f16x8*)(base + (h1 * 128 + w1) * 64 + c8);
  f16x8 o;
#pragma unroll
  for (int j = 0; j < 8; ++j)
    o[j] = (f16)(w00 * (float)a[j] + w01 * (float)b2[j] + w10 * (float)c[j] + w11 * (float)d[j]);
  *(f16x8*)(smp + (size_t)spt * 64 + c8) = o;
}

// ---------------- dense projection MLP via MFMA (fast gelu) ----------------
__global__ __launch_bounds__(256) void k_mlp(const f16* __restrict__ smp,
                                             const int4* __restrict__ pds,
                                             const f16* __restrict__ p1t,
                                             const float* __restrict__ p1b,
                                             const float* __restrict__ p2w, const float* __restrict__ p2b,
                                             float* __restrict__ out)
{
  __shared__ f16 s_in[128][72];
  __shared__ f16 s_p1[128][72];
  __shared__ float s_b1[128], s_p2[128];
  int blk = blockIdx.x, tid = threadIdx.x;
  for (int l = tid; l < 1024; l += 256) {
    int row = l >> 3, c8 = (l & 7) * 8;
    *(f16x8*)&s_in[row][c8] = *(const f16x8*)(smp + ((size_t)blk * 128 + row) * 64 + c8);
  }
  for (int l = tid; l < 1024; l += 256) {
    int j = l >> 3, c8 = (l & 7) * 8;
    *(f16x8*)&s_p1[j][c8] = *(const f16x8*)(p1t + j * 64 + c8);
  }
  if (tid < 128) { s_b1[tid] = p1b[tid]; s_p2[tid] = p2w[tid]; }
  __syncthreads();
  int wave = tid >> 6, lane = tid & 63, lr = lane & 15, lg = lane >> 4;
  f32x4 acc[2][8] = {};
#pragma unroll
  for (int ks = 0; ks < 2; ++ks) {
    f16x8 a[2], b[8];
#pragma unroll
    for (int mm = 0; mm < 2; ++mm) a[mm] = *(const f16x8*)&s_in[(wave * 2 + mm) * 16 + lr][ks * 32 + lg * 8];
#pragma unroll
    for (int nt = 0; nt < 8; ++nt) b[nt] = *(const f16x8*)&s_p1[nt * 16 + lr][ks * 32 + lg * 8];
#pragma unroll
    for (int mm = 0; mm < 2; ++mm)
#pragma unroll
      for (int nt = 0; nt < 8; ++nt)
        acc[mm][nt] = __builtin_amdgcn_mfma_f32_16x16x32_f16(a[mm], b[nt], acc[mm][nt], 0, 0, 0);
  }
  float p2b0 = p2b[0];
  float part[2][4] = {};
#pragma unroll
  for (int mm = 0; mm < 2; ++mm)
#pragma unroll
    for (int nt = 0; nt < 8; ++nt) {
#pragma unroll
      for (int r = 0; r < 4; ++r) {
        int j = nt * 16 + lr;
        part[mm][r] += gelu_fast(acc[mm][nt][r] + s_b1[j]) * s_p2[j];
      }
    }
#pragma unroll
  for (int mm = 0; mm < 2; ++mm)
#pragma unroll
    for (int r = 0; r < 4; ++r) {
      float v = part[mm][r];
      v += __shfl_xor(v, 1, 16);
      v += __shfl_xor(v, 2, 16);
      v += __shfl_xor(v, 4, 16);
      v += __shfl_xor(v, 8, 16);
      if (lr == 0) {
        int pt = (wave * 2 + mm) * 16 + lg * 4 + r;
        int opid = pds[blk * 128 + pt].x;
        out[opid] = v + p2b0;
      }
    }
}

extern "C" void kernel_launch(void* const* d_in, const int* in_sizes, int n_in,
                              void* d_out, int out_size, void* d_ws, size_t ws_size,
                              hipStream_t stream) {
  const float* coords = (const float*)d_in[0];
  const float* feats  = (const float*)d_in[1];
  const float* dw0 = (const float*)d_in[2];
  const float* db0 = (const float*)d_in[3];
  const float* dw1 = (const float*)d_in[4];
  const float* db1 = (const float*)d_in[5];
  const float* dw2 = (const float*)d_in[6];
  const float* db2 = (const float*)d_in[7];
  const float* liftw = (const float*)d_in[8];
  const float* liftb = (const float*)d_in[9];
  const float* sw1r = (const float*)d_in[10];
  const float* sw1i = (const float*)d_in[11];
  const float* sw2r = (const float*)d_in[12];
  const float* sw2i = (const float*)d_in[13];
  const float* pww = (const float*)d_in[14];
  const float* pwb = (const float*)d_in[15];
  const float* p1w = (const float*)d_in[16];
  const float* p1b = (const float*)d_in[17];
  const float* p2w = (const float*)d_in[18];
  const float* p2b = (const float*)d_in[19];
  float* out = (float*)d_out;
  char* base = (char*)d_ws;

  int*    cnt_i  = (int*)(base + 0);
  int*    ptrank = (int*)(base + 524288);
  int*    pd_cell= (int*)(base + 1048576);
  int*    starts = (int*)(base + 1572864);
  int*    btot   = (int*)(base + 2097152);
  int*    boff   = (int*)(base + 2098176);
  int*    pd_idx = (int*)(base + 2099200);
  float*  pd_th  = (float*)(base + 2623488);
  float*  pd_tw  = (float*)(base + 3147776);
  f16*    Gh     = (f16*)(base + 8388608);
  f16*    yh     = (f16*)(base + 25165824);
  f16*    smp    = (f16*)(base + 25165824);   // alias: yh dead after last k_inv
  float2* Xf2    = (float2*)(base + 41943040);
  float2* Yf2    = (float2*)(base + 46661632);
  int4*   pds    = (int4*)(base + 51380224);
  f16*    Gp     = (f16*)(base + 53477376);
  float4* scA    = (float4*)(base + 70254592);
  float*  scB    = (float*)(base + 72351744);
  f16*    Fw_t   = (f16*)(base + 87031808);
  f16*    Fh_t   = (f16*)(base + 87044096);
  f16*    Bh_t   = (f16*)(base + 87068672);
  f16*    Bw_t   = (f16*)(base + 87093248);
  f16*    p1t    = (f16*)(base + 87109632);

  hipMemsetAsync(cnt_i, 0, 524288, stream);

  k_twiddle<<<136, 256, 0, stream>>>(Fw_t, Fh_t, Bh_t, Bw_t, p1w, p1t);
  k_points<<<512, 256, 0, stream>>>(coords, dw0, db0, dw1, db1, dw2, db2,
                                    cnt_i, ptrank, pd_cell, pd_idx, pd_th, pd_tw);
  k_scanA<<<256, 256, 0, stream>>>(cnt_i, starts, btot);
  k_scanB<<<1, 256, 0, stream>>>(btot, boff);
  k_perm<<<512, 256, 0, stream>>>(pd_cell, ptrank, starts, boff, pd_idx, pd_th, pd_tw,
                                  coords, feats, pds, scA, scB);
  k_gridlift<<<dim3(128, 8), 256, 0, stream>>>(scA, scB, starts, boff, cnt_i, liftw, liftb, Gh);

  for (int d = 0; d < 4; ++d) {
    const int swoff = d * 2359296;
    k_fwdpw<<<1024, 256, 0, stream>>>(Gh, Fw_t, Fh_t, Xf2, pww + d * 4096, pwb + d * 64, yh);
    k_mix<<<dim3(9, 32, 2), 128, 0, stream>>>(Xf2, sw1r + swoff, sw1i + swoff,
                                              sw2r + swoff, sw2i + swoff, Yf2);
    k_inv<<<512, 256, 0, stream>>>(Yf2, Bh_t, Bw_t, yh, Gh);
  }

  k_tr<<<512, 256, 0, stream>>>(Gh, Gp);
  k_gather<<<4096, 256, 0, stream>>>(Gp, pds, smp);
  k_mlp<<<1024, 256, 0, stream>>>(smp, pds, p1t, p1b, p2w, p2b, out);
}

// Round 14
// 324.049 us; speedup vs baseline: 1.2014x; 1.0852x over previous
//
#include <hip/hip_runtime.h>
#include <math.h>

#define GH 128
#define GW 128
#define HWC 16384
#define NMODE 1152
#define PI_F 3.14159265358979323846f

typedef _Float16 f16;
typedef __attribute__((ext_vector_type(8))) _Float16 f16x8;
typedef __attribute__((ext_vector_type(4))) float f32x4;

// exact-path gelu (k_points only: feeds cell rounding, keep bit-compatible)
__device__ __forceinline__ float gelu_f(float x) {
  return 0.5f * x * (1.0f + erff(x * 0.70710678118654752f));
}

// fast gelu: A&S 7.1.26 erf (max abs err 1.5e-7), __expf -> v_exp_f32
__device__ __forceinline__ float gelu_fast(float x) {
  float ax = fabsf(x) * 0.70710678118654752f;
  float t = 1.f / fmaf(0.3275911f, ax, 1.f);
  float p = t * fmaf(t, fmaf(t, fmaf(t, fmaf(t, 1.061405429f, -1.453152027f),
                                     1.421413741f), -0.284496736f), 0.254829592f);
  float e = __expf(-ax * ax);
  float r = 1.f - p * e;
  r = copysignf(r, x);
  return 0.5f * x * (1.f + r);
}

// ---------------- prep: twiddle tables + f16-transposed p1 ----------------
__global__ __launch_bounds__(256) void k_twiddle(f16* __restrict__ Fw, f16* __restrict__ Fh,
                                                 f16* __restrict__ Bh, f16* __restrict__ Bw,
                                                 const float* __restrict__ p1w, f16* __restrict__ p1t)
{
  int idx = blockIdx.x * 256 + threadIdx.x;
  if (idx < 6144) {
    int n = idx >> 7, w = idx & 127;
    int ky = n >> 1;
    int ang = (ky * w) & 127;
    float s, c; sincosf((float)ang * (PI_F / 64.f), &s, &c);
    Fw[idx] = (f16)((n & 1) ? -s : c);
  } else if (idx < 18432) {
    int t = idx - 6144;
    int n = t >> 7, h = t & 127;
    int kx = n < 48 ? n : n - 48;
    int f = kx < 24 ? kx : kx + 80;
    int ang = (f * h) & 127;
    float s, c; sincosf((float)ang * (PI_F / 64.f), &s, &c);
    float v = (n < 48) ? c : s;
    Fh[t] = (f16)v;
    Bh[h * 96 + n] = (f16)v;
  } else if (idx < 26624) {
    int t = idx - 18432;
    int w = t >> 6, k = t & 63;
    float v = 0.f;
    if (k < 48 && k != 1) {
      int ky = k >> 1;
      float g = (ky == 0) ? 1.f : 2.f;
      int ang = (ky * w) & 127;
      float s, c; sincosf((float)ang * (PI_F / 64.f), &s, &c);
      v = (k & 1) ? -g * s : g * c;
    }
    Bw[t] = (f16)v;
  } else if (idx < 34816) {
    int t = idx - 26624;          // t = j*64 + i
    int j = t >> 6, i = t & 63;
    p1t[t] = (f16)p1w[i * 128 + j];
  }
}

// ---------------- points: deform MLP (f32, exact erf) + rank atomic + bilinear data ----------------
__global__ __launch_bounds__(256) void k_points(
    const float* __restrict__ coords,
    const float* __restrict__ dw0, const float* __restrict__ db0,
    const float* __restrict__ dw1, const float* __restrict__ db1,
    const float* __restrict__ dw2, const float* __restrict__ db2,
    int* __restrict__ cnt_i,
    int* __restrict__ ptrank, int* __restrict__ pd_cell,
    int* __restrict__ pd_idx, float* __restrict__ pd_th, float* __restrict__ pd_tw)
{
  int pid = blockIdx.x * 256 + threadIdx.x;
  float2 c = ((const float2*)coords)[pid];

  float h1[32];
#pragma unroll
  for (int j = 0; j < 32; ++j)
    h1[j] = gelu_f(fmaf(c.x, dw0[j], fmaf(c.y, dw0[32 + j], db0[j])));

  float a[32];
#pragma unroll
  for (int j = 0; j < 32; ++j) a[j] = db1[j];
#pragma unroll 4
  for (int k = 0; k < 32; ++k) {
    float hk = h1[k];
    const float* wr = dw1 + k * 32;
#pragma unroll
    for (int j = 0; j < 32; ++j) a[j] = fmaf(hk, wr[j], a[j]);
  }

  float d0 = db2[0], d1 = db2[1];
#pragma unroll 4
  for (int k = 0; k < 32; ++k) {
    float hk = gelu_f(a[k]);
    d0 = fmaf(hk, dw2[2 * k], d0);
    d1 = fmaf(hk, dw2[2 * k + 1], d1);
  }

  float l0 = fminf(fmaxf(c.x + d0, -1.f), 1.f);
  float l1 = fminf(fmaxf(c.y + d1, -1.f), 1.f);
  float ph = (l0 + 1.f) * 0.5f * 127.f;
  float pw = (l1 + 1.f) * 0.5f * 127.f;
  int ih = min(max((int)rintf(ph), 0), 127);
  int iw = min(max((int)rintf(pw), 0), 127);
  int b = pid >> 14;
  int cell = b * HWC + ih * GW + iw;

  int r = atomicAdd(&cnt_i[cell], 1);
  ptrank[pid] = r;
  pd_cell[pid] = cell;

  float fh = floorf(ph), fw = floorf(pw);
  int h0i = min(max((int)fh, 0), 127), w0i = min(max((int)fw, 0), 127);
  pd_idx[pid] = h0i | (w0i << 8);
  pd_th[pid] = ph - fh;
  pd_tw[pid] = pw - fw;
}

// ---------------- scans ----------------
__global__ __launch_bounds__(256) void k_scanA(const int* __restrict__ cnt,
                                               int* __restrict__ starts, int* __restrict__ btot)
{
  __shared__ int sh[256];
  int blk = blockIdx.x, t = threadIdx.x;
  int base = blk * 512;
  int v0 = cnt[base + 2 * t], v1 = cnt[base + 2 * t + 1];
  int pair = v0 + v1;
  sh[t] = pair; __syncthreads();
  int acc = pair;
  for (int off = 1; off < 256; off <<= 1) {
    int add = (t >= off) ? sh[t - off] : 0;
    __syncthreads();
    acc += add; sh[t] = acc;
    __syncthreads();
  }
  int excl = acc - pair;
  starts[base + 2 * t] = excl;
  starts[base + 2 * t + 1] = excl + v0;
  if (t == 255) btot[blk] = acc;
}

__global__ __launch_bounds__(256) void k_scanB(const int* __restrict__ btot, int* __restrict__ boff)
{
  __shared__ int sh[256];
  int t = threadIdx.x;
  int v = btot[t];
  sh[t] = v; __syncthreads();
  int acc = v;
  for (int off = 1; off < 256; off <<= 1) {
    int add = (t >= off) ? sh[t - off] : 0;
    __syncthreads();
    acc += add; sh[t] = acc;
    __syncthreads();
  }
  boff[t] = acc - v;
}

// ---------------- permute ----------------
__global__ __launch_bounds__(256) void k_perm(const int* __restrict__ pd_cell, const int* __restrict__ ptrank,
                                              const int* __restrict__ starts, const int* __restrict__ boff,
                                              const int* __restrict__ pd_idx, const float* __restrict__ pd_th,
                                              const float* __restrict__ pd_tw,
                                              const float* __restrict__ coords, const float* __restrict__ feats,
                                              int4* __restrict__ pds,
                                              float4* __restrict__ scA, float* __restrict__ scB)
{
  int pid = blockIdx.x * 256 + threadIdx.x;
  int cell = pd_cell[pid];
  int dst = starts[cell] + boff[cell >> 9] + ptrank[pid];
  int4 rec;
  rec.x = pid;
  rec.y = pd_idx[pid];
  rec.z = __float_as_int(pd_th[pid]);
  rec.w = __float_as_int(pd_tw[pid]);
  pds[dst] = rec;
  float2 c = ((const float2*)coords)[pid];
  scA[dst] = make_float4(feats[pid * 3], feats[pid * 3 + 1], feats[pid * 3 + 2], c.x);
  scB[dst] = c.y;
}

// ---------------- segmented cell-sum + lift -> Gh (f16) ----------------
__global__ __launch_bounds__(256) void k_gridlift(const float4* __restrict__ scA, const float* __restrict__ scB,
                                                  const int* __restrict__ starts, const int* __restrict__ boff,
                                                  const int* __restrict__ cnt_i,
                                                  const float* __restrict__ lw,
                                                  const float* __restrict__ lb,
                                                  f16* __restrict__ Gh)
{
  __shared__ float sp[2][128][5];
  __shared__ float s_lw[5][64];
  __shared__ float s_lb[64];
  __shared__ float s_cnt[128];
  int b = blockIdx.y, cbase = blockIdx.x * 128, tid = threadIdx.x;
  int cl = tid & 127, par = tid >> 7;
  int gcell = b * HWC + cbase + cl;
  int start = starts[gcell] + boff[gcell >> 9];
  int cnt = cnt_i[gcell];
  float a0 = 0.f, a1 = 0.f, a2 = 0.f, a3 = 0.f, a4 = 0.f;
  for (int p = start + par; p < start + cnt; p += 2) {
    float4 A = scA[p];
    a0 += A.x; a1 += A.y; a2 += A.z; a3 += A.w; a4 += scB[p];
  }
  sp[par][cl][0] = a0; sp[par][cl][1] = a1; sp[par][cl][2] = a2;
  sp[par][cl][3] = a3; sp[par][cl][4] = a4;
  if (par == 0) s_cnt[cl] = (float)cnt;
  for (int l = tid; l < 320; l += 256) ((float*)s_lw)[l] = lw[l];
  if (tid < 64) s_lb[tid] = lb[tid];
  __syncthreads();
  float v0 = sp[0][cl][0] + sp[1][cl][0];
  float v1 = sp[0][cl][1] + sp[1][cl][1];
  float v2 = sp[0][cl][2] + sp[1][cl][2];
  float v3 = sp[0][cl][3] + sp[1][cl][3];
  float v4 = sp[0][cl][4] + sp[1][cl][4];
  float cntf = s_cnt[cl];
  float inv = 1.f / fmaxf(cntf, 1.f);
  int oh = tid >> 7;
#pragma unroll
  for (int j = 0; j < 32; ++j) {
    int o = oh * 32 + j;
    float val = cntf * s_lb[o];
    val = fmaf(v0, s_lw[0][o], val);
    val = fmaf(v1, s_lw[1][o], val);
    val = fmaf(v2, s_lw[2][o], val);
    val = fmaf(v3, s_lw[3][o], val);
    val = fmaf(v4, s_lw[4][o], val);
    Gh[(size_t)(b * 64 + o) * HWC + cbase + cl] = (f16)(val * inv);
  }
}

// ---------------- fused forward DFT (blocks 0..511) + pointwise conv (blocks 512..1023) ----------------
__global__ __launch_bounds__(256) void k_fwdpw(const f16* __restrict__ Gh,
                                               const f16* __restrict__ Fw_t, const f16* __restrict__ Fh_t,
                                               float2* __restrict__ Xf2,
                                               const float* __restrict__ pww, const float* __restrict__ pwb,
                                               f16* __restrict__ yh)
{
  __shared__ char smem[52224];
  int tid = threadIdx.x;
  int wave = tid >> 6, lane = tid & 63, lr = lane & 15, lg = lane >> 4;

  if (blockIdx.x < 512) {
    // ---- forward DFT ----
    f16 (*s_fw)[136]  = (f16(*)[136])smem;
    f16 (*s_img)[136] = (f16(*)[136])(smem + 13056);
    f16 (*s_xw)[136]  = (f16(*)[136])(smem + 13056);
    f16 (*s_fh)[136]  = (f16(*)[136])(smem + 13056 + 48 * 136 * 2);
    int bc = blockIdx.x;
    for (int l = tid; l < 2048; l += 256) {
      int r = l >> 4, c = l & 15;
      *(f16x8*)&s_img[r][c * 8] = *(const f16x8*)(Gh + (size_t)bc * HWC + r * 128 + c * 8);
    }
    for (int l = tid; l < 768; l += 256) {
      int r = l >> 4, c = l & 15;
      *(f16x8*)&s_fw[r][c * 8] = *(const f16x8*)(Fw_t + r * 128 + c * 8);
    }
    __syncthreads();

    f32x4 acc1[2][3] = {};
#pragma unroll
    for (int ks = 0; ks < 4; ++ks) {
      f16x8 a[2], b[3];
#pragma unroll
      for (int mm = 0; mm < 2; ++mm) a[mm] = *(const f16x8*)&s_img[(wave * 2 + mm) * 16 + lr][ks * 32 + lg * 8];
#pragma unroll
      for (int nt = 0; nt < 3; ++nt) b[nt] = *(const f16x8*)&s_fw[nt * 16 + lr][ks * 32 + lg * 8];
#pragma unroll
      for (int mm = 0; mm < 2; ++mm)
#pragma unroll
        for (int nt = 0; nt < 3; ++nt)
          acc1[mm][nt] = __builtin_amdgcn_mfma_f32_16x16x32_f16(a[mm], b[nt], acc1[mm][nt], 0, 0, 0);
    }
    __syncthreads();
#pragma unroll
    for (int mm = 0; mm < 2; ++mm)
#pragma unroll
      for (int nt = 0; nt < 3; ++nt) {
        int n = nt * 16 + lr;
        int h0 = (wave * 2 + mm) * 16 + lg * 4;
#pragma unroll
        for (int r = 0; r < 4; ++r) s_xw[n][h0 + r] = (f16)acc1[mm][nt][r];
      }
    for (int l = tid; l < 1536; l += 256) {
      int r = l >> 4, c = l & 15;
      *(f16x8*)&s_fh[r][c * 8] = *(const f16x8*)(Fh_t + r * 128 + c * 8);
    }
    __syncthreads();

    for (int u = wave; u < 9; u += 4) {
      int mt = u / 3, ntC = u - mt * 3;
      f32x4 accC = {}, accS = {};
#pragma unroll
      for (int ks = 0; ks < 4; ++ks) {
        f16x8 a  = *(const f16x8*)&s_xw[mt * 16 + lr][ks * 32 + lg * 8];
        f16x8 bC = *(const f16x8*)&s_fh[ntC * 16 + lr][ks * 32 + lg * 8];
        f16x8 bS = *(const f16x8*)&s_fh[(ntC + 3) * 16 + lr][ks * 32 + lg * 8];
        accC = __builtin_amdgcn_mfma_f32_16x16x32_f16(a, bC, accC, 0, 0, 0);
        accS = __builtin_amdgcn_mfma_f32_16x16x32_f16(a, bS, accS, 0, 0, 0);
      }
      int kx = ntC * 16 + lr;
      int ky0 = (mt * 16 + lg * 4) >> 1;
      Xf2[bc * NMODE + kx * 24 + ky0]     = make_float2(accC[0] + accS[1], accC[1] - accS[0]);
      Xf2[bc * NMODE + kx * 24 + ky0 + 1] = make_float2(accC[2] + accS[3], accC[3] - accS[2]);
    }
  } else {
    // ---- pointwise conv (XOR-swizzled LDS staging) ----
    f16 (*gt)[72] = (f16(*)[72])smem;
    f16 (*wt)[72] = (f16(*)[72])(smem + 36864);
    float* s_b    = (float*)(smem + 46080);
    int blk = blockIdx.x - 512;
    int b = blk >> 6, p0 = (blk & 63) * 256;
    for (int l = tid; l < 4096; l += 256) {
      int i = l >> 6, o = l & 63;
      wt[o][i ^ (((o >> 3) & 7) << 3)] = (f16)pww[l];
    }
    if (tid < 64) s_b[tid] = pwb[tid];
    for (int l = tid; l < 2048; l += 256) {
      int i = l >> 5, pc = (l & 31) * 8;
      f16x8 v = *(const f16x8*)(Gh + (size_t)(b * 64 + i) * HWC + p0 + pc);
      int sw = (l & 7) << 3;
#pragma unroll
      for (int j = 0; j < 8; ++j) gt[pc + j][i ^ sw] = v[j];
    }
    __syncthreads();
    int pw_ = wave * 64;
    f32x4 acc[4][4] = {};
#pragma unroll
    for (int kk = 0; kk < 2; ++kk) {
      f16x8 a[4], bb[4];
#pragma unroll
      for (int mi = 0; mi < 4; ++mi) {
        int o = 16 * mi + lr;
        a[mi] = *(const f16x8*)&wt[o][(kk * 32 + lg * 8) ^ (((o >> 3) & 7) << 3)];
      }
#pragma unroll
      for (int ni = 0; ni < 4; ++ni) {
        int p = pw_ + 16 * ni + lr;
        bb[ni] = *(const f16x8*)&gt[p][(kk * 32 + lg * 8) ^ (((p >> 3) & 7) << 3)];
      }
#pragma unroll
      for (int mi = 0; mi < 4; ++mi)
#pragma unroll
        for (int ni = 0; ni < 4; ++ni)
          acc[mi][ni] = __builtin_amdgcn_mfma_f32_16x16x32_f16(a[mi], bb[ni], acc[mi][ni], 0, 0, 0);
    }
    __syncthreads();
    f16 (*s_o)[264] = (f16(*)[264])smem;
#pragma unroll
    for (int mi = 0; mi < 4; ++mi)
#pragma unroll
      for (int ni = 0; ni < 4; ++ni) {
#pragma unroll
        for (int r = 0; r < 4; ++r) {
          int o = 16 * mi + lg * 4 + r;
          s_o[o][pw_ + 16 * ni + lr] = (f16)(acc[mi][ni][r] + s_b[o]);
        }
      }
    __syncthreads();
    for (int l = tid; l < 2048; l += 256) {
      int o = l >> 5, pc = (l & 31) * 8;
      *(f16x8*)(yh + (size_t)(b * 64 + o) * HWC + p0 + pc) = *(const f16x8*)&s_o[o][pc];
    }
  }
}

// ---------------- per-mode 64x64 complex channel mix: i-split x4 partials ----------------
// grid (9, 32, 8): z = half*4 + ichunk; each block does i in [ic*16, ic*16+16)
__global__ __launch_bounds__(128) void k_mix(const float2* __restrict__ Xf2,
    const float* __restrict__ w1r, const float* __restrict__ w1i,
    const float* __restrict__ w2r, const float* __restrict__ w2i,
    float2* __restrict__ Yp)
{
  int m = blockIdx.x * 64 + (threadIdx.x & 63);
  int o = blockIdx.y * 2 + (threadIdx.x >> 6);
  int half = blockIdx.z >> 2;
  int ic = blockIdx.z & 3;
  int gm = half * 576 + m;
  const float* wr_ = half ? w2r : w1r;
  const float* wi_ = half ? w2i : w1i;
  float aR[8] = {}, aI[8] = {};
  int i0 = ic * 16;
#pragma unroll 4
  for (int ii = 0; ii < 16; ++ii) {
    int i = i0 + ii;
    int widx = (i * 64 + o) * 576 + m;
    float wr = wr_[widx], wi = wi_[widx];
#pragma unroll
    for (int b = 0; b < 8; ++b) {
      float2 x = Xf2[(b * 64 + i) * NMODE + gm];
      aR[b] = fmaf(x.x, wr, aR[b]); aR[b] = fmaf(-x.y, wi, aR[b]);
      aI[b] = fmaf(x.x, wi, aI[b]); aI[b] = fmaf(x.y, wr, aI[b]);
    }
  }
#pragma unroll
  for (int b = 0; b < 8; ++b)
    Yp[(size_t)ic * 589824 + (b * 64 + o) * NMODE + gm] = make_float2(aR[b], aI[b]);
}

// ---------------- inverse DFT (partial-reduce + two fused MFMA GEMMs) + add + instnorm + gelu ----------------
__global__ __launch_bounds__(256) void k_inv(const float2* __restrict__ Yp,
                                             const f16* __restrict__ Bh_t, const f16* __restrict__ Bw_t,
                                             const f16* __restrict__ yh, f16* __restrict__ Gh)
{
  __shared__ f16 s_u[21120];
  __shared__ float rs[256], rq[256];
  __shared__ float s_mu, s_rstd;
  f16 (*s_a)[120]  = (f16(*)[120])s_u;
  f16 (*s_bh)[120] = (f16(*)[120])(s_u + 48 * 120);
  f16 (*s_t)[72]   = (f16(*)[72])s_u;
  f16 (*s_bw)[72]  = (f16(*)[72])(s_u + 128 * 72);
  f16 (*s_y)[136]  = (f16(*)[136])s_u;
  int bc = blockIdx.x, tid = threadIdx.x;

  for (int l = tid; l < 1152; l += 256) {
    int kx = l / 24, ky = l - kx * 24;
    float2 y0 = Yp[(size_t)bc * NMODE + l];
    float2 y1 = Yp[589824 + (size_t)bc * NMODE + l];
    float2 y2 = Yp[2 * 589824 + (size_t)bc * NMODE + l];
    float2 y3 = Yp[3 * 589824 + (size_t)bc * NMODE + l];
    float yr = (y0.x + y1.x) + (y2.x + y3.x);
    float yi = (y0.y + y1.y) + (y2.y + y3.y);
    s_a[2 * ky][kx]          = (f16)yr;
    s_a[2 * ky][48 + kx]     = (f16)(-yi);
    s_a[2 * ky + 1][kx]      = (f16)yi;
    s_a[2 * ky + 1][48 + kx] = (f16)yr;
  }
  for (int l = tid; l < 1536; l += 256) {
    int r = l / 12, c = l - r * 12;
    *(f16x8*)&s_bh[r][c * 8] = *(const f16x8*)(Bh_t + r * 96 + c * 8);
  }
  __syncthreads();
  int wave = tid >> 6, lane = tid & 63, lr = lane & 15, lg = lane >> 4;

  f32x4 acc_a[6];
#pragma unroll
  for (int i = 0; i < 6; ++i) acc_a[i] = (f32x4){0.f, 0.f, 0.f, 0.f};
#pragma unroll
  for (int i = 0; i < 6; ++i) {
    int t = wave + 4 * i;
    int mt = t >> 3, nt = t & 7;
#pragma unroll
    for (int ks = 0; ks < 3; ++ks) {
      f16x8 a = *(const f16x8*)&s_a[mt * 16 + lr][ks * 32 + lg * 8];
      f16x8 b = *(const f16x8*)&s_bh[nt * 16 + lr][ks * 32 + lg * 8];
      acc_a[i] = __builtin_amdgcn_mfma_f32_16x16x32_f16(a, b, acc_a[i], 0, 0, 0);
    }
  }
  __syncthreads();
#pragma unroll
  for (int i = 0; i < 6; ++i) {
    int t = wave + 4 * i;
    int mt = t >> 3, nt = t & 7;
    int h = nt * 16 + lr;
    int m0 = mt * 16 + lg * 4;
#pragma unroll
    for (int r = 0; r < 4; ++r) s_t[h][m0 + r] = (f16)acc_a[i][r];
  }
  for (int l = tid; l < 2048; l += 256) {
    int h = l >> 4, c = 48 + (l & 15);
    s_t[h][c] = (f16)0.f;
  }
  for (int l = tid; l < 1024; l += 256) {
    int r = l >> 3, c = l & 7;
    *(f16x8*)&s_bw[r][c * 8] = *(const f16x8*)(Bw_t + r * 64 + c * 8);
  }
  __syncthreads();

  f32x4 acc_b[2][8] = {};
#pragma unroll
  for (int ks = 0; ks < 2; ++ks) {
    f16x8 a[2], b[8];
#pragma unroll
    for (int mm = 0; mm < 2; ++mm) a[mm] = *(const f16x8*)&s_t[(wave * 2 + mm) * 16 + lr][ks * 32 + lg * 8];
#pragma unroll
    for (int nt = 0; nt < 8; ++nt) b[nt] = *(const f16x8*)&s_bw[nt * 16 + lr][ks * 32 + lg * 8];
#pragma unroll
    for (int mm = 0; mm < 2; ++mm)
#pragma unroll
      for (int nt = 0; nt < 8; ++nt)
        acc_b[mm][nt] = __builtin_amdgcn_mfma_f32_16x16x32_f16(a[mm], b[nt], acc_b[mm][nt], 0, 0, 0);
  }
  __syncthreads();
  for (int l = tid; l < 2048; l += 256) {
    int r = l >> 4, c = l & 15;
    *(f16x8*)&s_y[r][c * 8] = *(const f16x8*)(yh + (size_t)bc * HWC + r * 128 + c * 8);
  }
  __syncthreads();
  float sum = 0.f, ssq = 0.f;
#pragma unroll
  for (int mm = 0; mm < 2; ++mm)
#pragma unroll
    for (int nt = 0; nt < 8; ++nt)
#pragma unroll
      for (int r = 0; r < 4; ++r) {
        int h = (wave * 2 + mm) * 16 + lg * 4 + r;
        int w = nt * 16 + lr;
        float v = acc_b[mm][nt][r] * (1.f / 16384.f) + (float)s_y[h][w];
        acc_b[mm][nt][r] = v;
        sum += v; ssq = fmaf(v, v, ssq);
      }
  rs[tid] = sum; rq[tid] = ssq;
  __syncthreads();
  for (int sft = 128; sft > 0; sft >>= 1) {
    if (tid < sft) { rs[tid] += rs[tid + sft]; rq[tid] += rq[tid + sft]; }
    __syncthreads();
  }
  if (tid == 0) {
    float mu = rs[0] * (1.f / 16384.f);
    float var = fmaxf(rq[0] * (1.f / 16384.f) - mu * mu, 0.f);
    s_mu = mu;
    s_rstd = rsqrtf(var + 1e-5f);
  }
  __syncthreads();
  float mu = s_mu, rstd = s_rstd;
#pragma unroll
  for (int mm = 0; mm < 2; ++mm)
#pragma unroll
    for (int nt = 0; nt < 8; ++nt)
#pragma unroll
      for (int r = 0; r < 4; ++r) {
        int h = (wave * 2 + mm) * 16 + lg * 4 + r;
        int w = nt * 16 + lr;
        s_y[h][w] = (f16)gelu_fast((acc_b[mm][nt][r] - mu) * rstd);
      }
  __syncthreads();
  for (int l = tid; l < 2048; l += 256) {
    int r = l >> 4, c = l & 15;
    *(f16x8*)(Gh + (size_t)bc * HWC + r * 128 + c * 8) = *(const f16x8*)&s_y[r][c * 8];
  }
}

// ---------------- transpose final grid ----------------
__global__ __launch_bounds__(256) void k_tr(const f16* __restrict__ Gh, f16* __restrict__ Gp)
{
  __shared__ f16 t[64][264];
  int b = blockIdx.x >> 6, cell0 = (blockIdx.x & 63) * 256, tid = threadIdx.x;
  for (int l = tid; l < 2048; l += 256) {
    int c = l >> 5, q = l & 31;
    *(f16x8*)&t[c][q * 8] = *(const f16x8*)(Gh + (size_t)(b * 64 + c) * HWC + cell0 + q * 8);
  }
  __syncthreads();
  int cell = tid;
  f16* dst = Gp + ((size_t)b * HWC + cell0 + cell) * 64;
#pragma unroll
  for (int q = 0; q < 8; ++q) {
    f16x8 v;
#pragma unroll
    for (int j = 0; j < 8; ++j) v[j] = t[q * 8 + j][cell];
    *(f16x8*)(dst + q * 8) = v;
  }
}

// ---------------- gather: 1 thread per (point, 8ch) ----------------
__global__ __launch_bounds__(256) void k_gather(const f16* __restrict__ Gp,
                                                const int4* __restrict__ pds,
                                                f16* __restrict__ smp)
{
  int idx = blockIdx.x * 256 + threadIdx.x;
  int spt = idx >> 3, c8 = (idx & 7) * 8;
  int4 rec = pds[spt];
  int b = rec.x >> 14;
  int h0 = rec.y & 255, w0 = (rec.y >> 8) & 255;
  int h1 = min(h0 + 1, 127), w1 = min(w0 + 1, 127);
  float th = __int_as_float(rec.z), tw = __int_as_float(rec.w);
  float w00 = (1.f - th) * (1.f - tw), w01 = (1.f - th) * tw;
  float w10 = th * (1.f - tw), w11 = th * tw;
  const f16* base = Gp + (((size_t)b << 14) << 6);
  f16x8 a  = *(const f16x8*)(base + (h0 * 128 + w0) * 64 + c8);
  f16x8 b2 = *(const f16x8*)(base + (h0 * 128 + w1) * 64 + c8);
  f16x8 c  = *(const f16x8*)(base + (h1 * 128 + w0) * 64 + c8);
  f16x8 d  = *(const f16x8*)(base + (h1 * 128 + w1) * 64 + c8);
  f16x8 o;
#pragma unroll
  for (int j = 0; j < 8; ++j)
    o[j] = (f16)(w00 * (float)a[j] + w01 * (float)b2[j] + w10 * (float)c[j] + w11 * (float)d[j]);
  *(f16x8*)(smp + (size_t)spt * 64 + c8) = o;
}

// ---------------- dense projection MLP via MFMA (fast gelu) ----------------
__global__ __launch_bounds__(256) void k_mlp(const f16* __restrict__ smp,
                                             const int4* __restrict__ pds,
                                             const f16* __restrict__ p1t,
                                             const float* __restrict__ p1b,
                                             const float* __restrict__ p2w, const float* __restrict__ p2b,
                                             float* __restrict__ out)
{
  __shared__ f16 s_in[128][72];
  __shared__ f16 s_p1[128][72];
  __shared__ float s_b1[128], s_p2[128];
  int blk = blockIdx.x, tid = threadIdx.x;
  for (int l = tid; l < 1024; l += 256) {
    int row = l >> 3, c8 = (l & 7) * 8;
    *(f16x8*)&s_in[row][c8] = *(const f16x8*)(smp + ((size_t)blk * 128 + row) * 64 + c8);
  }
  for (int l = tid; l < 1024; l += 256) {
    int j = l >> 3, c8 = (l & 7) * 8;
    *(f16x8*)&s_p1[j][c8] = *(const f16x8*)(p1t + j * 64 + c8);
  }
  if (tid < 128) { s_b1[tid] = p1b[tid]; s_p2[tid] = p2w[tid]; }
  __syncthreads();
  int wave = tid >> 6, lane = tid & 63, lr = lane & 15, lg = lane >> 4;
  f32x4 acc[2][8] = {};
#pragma unroll
  for (int ks = 0; ks < 2; ++ks) {
    f16x8 a[2], b[8];
#pragma unroll
    for (int mm = 0; mm < 2; ++mm) a[mm] = *(const f16x8*)&s_in[(wave * 2 + mm) * 16 + lr][ks * 32 + lg * 8];
#pragma unroll
    for (int nt = 0; nt < 8; ++nt) b[nt] = *(const f16x8*)&s_p1[nt * 16 + lr][ks * 32 + lg * 8];
#pragma unroll
    for (int mm = 0; mm < 2; ++mm)
#pragma unroll
      for (int nt = 0; nt < 8; ++nt)
        acc[mm][nt] = __builtin_amdgcn_mfma_f32_16x16x32_f16(a[mm], b[nt], acc[mm][nt], 0, 0, 0);
  }
  float p2b0 = p2b[0];
  float part[2][4] = {};
#pragma unroll
  for (int mm = 0; mm < 2; ++mm)
#pragma unroll
    for (int nt = 0; nt < 8; ++nt) {
#pragma unroll
      for (int r = 0; r < 4; ++r) {
        int j = nt * 16 + lr;
        part[mm][r] += gelu_fast(acc[mm][nt][r] + s_b1[j]) * s_p2[j];
      }
    }
#pragma unroll
  for (int mm = 0; mm < 2; ++mm)
#pragma unroll
    for (int r = 0; r < 4; ++r) {
      float v = part[mm][r];
      v += __shfl_xor(v, 1, 16);
      v += __shfl_xor(v, 2, 16);
      v += __shfl_xor(v, 4, 16);
      v += __shfl_xor(v, 8, 16);
      if (lr == 0) {
        int pt = (wave * 2 + mm) * 16 + lg * 4 + r;
        int opid = pds[blk * 128 + pt].x;
        out[opid] = v + p2b0;
      }
    }
}

extern "C" void kernel_launch(void* const* d_in, const int* in_sizes, int n_in,
                              void* d_out, int out_size, void* d_ws, size_t ws_size,
                              hipStream_t stream) {
  const float* coords = (const float*)d_in[0];
  const float* feats  = (const float*)d_in[1];
  const float* dw0 = (const float*)d_in[2];
  const float* db0 = (const float*)d_in[3];
  const float* dw1 = (const float*)d_in[4];
  const float* db1 = (const float*)d_in[5];
  const float* dw2 = (const float*)d_in[6];
  const float* db2 = (const float*)d_in[7];
  const float* liftw = (const float*)d_in[8];
  const float* liftb = (const float*)d_in[9];
  const float* sw1r = (const float*)d_in[10];
  const float* sw1i = (const float*)d_in[11];
  const float* sw2r = (const float*)d_in[12];
  const float* sw2i = (const float*)d_in[13];
  const float* pww = (const float*)d_in[14];
  const float* pwb = (const float*)d_in[15];
  const float* p1w = (const float*)d_in[16];
  const float* p1b = (const float*)d_in[17];
  const float* p2w = (const float*)d_in[18];
  const float* p2b = (const float*)d_in[19];
  float* out = (float*)d_out;
  char* base = (char*)d_ws;

  int*    cnt_i  = (int*)(base + 0);
  int*    ptrank = (int*)(base + 524288);
  int*    pd_cell= (int*)(base + 1048576);
  int*    starts = (int*)(base + 1572864);
  int*    btot   = (int*)(base + 2097152);
  int*    boff   = (int*)(base + 2098176);
  int*    pd_idx = (int*)(base + 2099200);
  float*  pd_th  = (float*)(base + 2623488);
  float*  pd_tw  = (float*)(base + 3147776);
  f16*    Gh     = (f16*)(base + 8388608);
  f16*    yh     = (f16*)(base + 25165824);
  f16*    smp    = (f16*)(base + 25165824);   // alias: yh dead after last k_inv
  float2* Xf2    = (float2*)(base + 41943040);
  int4*   pds    = (int4*)(base + 51380224);
  f16*    Gp     = (f16*)(base + 53477376);
  float2* Yp     = (float2*)(base + 53477376); // alias: 18.9 MB over Gp+scA (dead during layers)
  float4* scA    = (float4*)(base + 70254592);
  float*  scB    = (float*)(base + 72351744);
  f16*    Fw_t   = (f16*)(base + 87031808);
  f16*    Fh_t   = (f16*)(base + 87044096);
  f16*    Bh_t   = (f16*)(base + 87068672);
  f16*    Bw_t   = (f16*)(base + 87093248);
  f16*    p1t    = (f16*)(base + 87109632);

  hipMemsetAsync(cnt_i, 0, 524288, stream);

  k_twiddle<<<136, 256, 0, stream>>>(Fw_t, Fh_t, Bh_t, Bw_t, p1w, p1t);
  k_points<<<512, 256, 0, stream>>>(coords, dw0, db0, dw1, db1, dw2, db2,
                                    cnt_i, ptrank, pd_cell, pd_idx, pd_th, pd_tw);
  k_scanA<<<256, 256, 0, stream>>>(cnt_i, starts, btot);
  k_scanB<<<1, 256, 0, stream>>>(btot, boff);
  k_perm<<<512, 256, 0, stream>>>(pd_cell, ptrank, starts, boff, pd_idx, pd_th, pd_tw,
                                  coords, feats, pds, scA, scB);
  k_gridlift<<<dim3(128, 8), 256, 0, stream>>>(scA, scB, starts, boff, cnt_i, liftw, liftb, Gh);

  for (int d = 0; d < 4; ++d) {
    const int swoff = d * 2359296;
    k_fwdpw<<<1024, 256, 0, stream>>>(Gh, Fw_t, Fh_t, Xf2, pww + d * 4096, pwb + d * 64, yh);
    k_mix<<<dim3(9, 32, 8), 128, 0, stream>>>(Xf2, sw1r + swoff, sw1i + swoff,
                                              sw2r + swoff, sw2i + swoff, Yp);
    k_inv<<<512, 256, 0, stream>>>(Yp, Bh_t, Bw_t, yh, Gh);
  }

  k_tr<<<512, 256, 0, stream>>>(Gh, Gp);
  k_gather<<<4096, 256, 0, stream>>>(Gp, pds, smp);
  k_mlp<<<1024, 256, 0, stream>>>(smp, pds, p1t, p1b, p2w, p2b, out);
}